// Round 5
// baseline (337.371 us; speedup 1.0000x reference)
//
#include <hip/hip_runtime.h>

#define NROWS 8192  // BT * N = 8 * 1024

typedef float f32x4 __attribute__((ext_vector_type(4)));
typedef __bf16 bf16x8 __attribute__((ext_vector_type(8)));

// ---------------------------------------------------------------------------
// K1: LayerNorm over D=256 + transpose to K-major xnT[d][bt*1024+n]
// 256 blocks x 256 thr; block = 32 rows; 8 parts x 32 d's each.
// ---------------------------------------------------------------------------
__global__ __launch_bounds__(256) void ln_kernel(const float* __restrict__ x,
                                                 const float* __restrict__ gamma,
                                                 const float* __restrict__ beta,
                                                 float* __restrict__ xnT) {
  __shared__ float red[2][8][32];
  const int blk = blockIdx.x;  // 256 = bt(8) x nchunk(32)
  const int bt = blk >> 5;
  const int b = bt >> 2, t = bt & 3;
  const int n0 = (blk & 31) << 5;
  const int part = threadIdx.x >> 5, r = threadIdx.x & 31;
  const int n = n0 + r;
  const float* xp = x + ((size_t)(b * 256) * 4 + t) * 1024 + n;  // d stride 4096
  float sum = 0.f, sumsq = 0.f;
#pragma unroll 8
  for (int dd = 0; dd < 32; ++dd) {
    float vv = xp[(size_t)(part * 32 + dd) * 4096];
    sum += vv;
    sumsq += vv * vv;
  }
  red[0][part][r] = sum;
  red[1][part][r] = sumsq;
  __syncthreads();
  float s1 = 0.f, s2 = 0.f;
#pragma unroll
  for (int p = 0; p < 8; ++p) {
    s1 += red[0][p][r];
    s2 += red[1][p][r];
  }
  const float mu = s1 * (1.0f / 256.0f);
  const float var = s2 * (1.0f / 256.0f) - mu * mu;
  const float rstd = rsqrtf(var + 1e-6f);
  float* outp = xnT + (size_t)bt * 1024 + n;
#pragma unroll 8
  for (int dd = 0; dd < 32; ++dd) {
    const int d = part * 32 + dd;
    float vv = xp[(size_t)d * 4096];
    outp[(size_t)d * NROWS] = (vv - mu) * rstd * gamma[d] + beta[d];
  }
}

// ---------------------------------------------------------------------------
// K2: 5 projections, 128x128 tile, 8x8 micro (split 4+4 rows/cols), fp32.
// C[m][o] = sum_d xnT[d][m] * W[o][d]. grid (64, 2, 5).
// ---------------------------------------------------------------------------
__global__ __launch_bounds__(256) void proj_kernel(
    const float* __restrict__ xnT,
    const float* __restrict__ Wq, const float* __restrict__ Wk,
    const float* __restrict__ Wv, const float* __restrict__ Wkl,
    const float* __restrict__ Wvl, const float* __restrict__ qb,
    float* __restrict__ qf, __bf16* __restrict__ qh_g, __bf16* __restrict__ ql_g,
    __bf16* __restrict__ kh_g, __bf16* __restrict__ kl_g,
    __bf16* __restrict__ vhT_g, __bf16* __restrict__ vlT_g,
    float* __restrict__ kloc, float* __restrict__ vloc) {
  __shared__ float As[16][128];
  __shared__ float Bs[16][132];
  const int z = blockIdx.z;
  const float* Wm = (z == 0) ? Wq : (z == 1) ? Wk : (z == 2) ? Wv : (z == 3) ? Wkl : Wvl;
  const int m0 = blockIdx.x * 128;
  const int o0 = blockIdx.y * 128;
  const int tid = threadIdx.x;
  const int tx = tid & 15, ty = tid >> 4;
  float c[8][8] = {};
#pragma unroll 1
  for (int k0 = 0; k0 < 256; k0 += 16) {
    {  // stage A: 2048 elems, 8/thread, coalesced along m
      const int m = tid & 127, kq = tid >> 7;
#pragma unroll
      for (int rr = 0; rr < 8; ++rr)
        As[kq + rr * 2][m] = xnT[(size_t)(k0 + kq + rr * 2) * NROWS + m0 + m];
    }
    {  // stage B: 2048 elems, 8/thread, coalesced along k
      const int kb = tid & 15, ob = tid >> 4;
#pragma unroll
      for (int rr = 0; rr < 8; ++rr)
        Bs[kb][ob + rr * 16] = Wm[(size_t)(o0 + ob + rr * 16) * 256 + k0 + kb];
    }
    __syncthreads();
#pragma unroll
    for (int kk = 0; kk < 16; ++kk) {
      const f32x4 a0 = *(const f32x4*)&As[kk][tx * 4];
      const f32x4 a1 = *(const f32x4*)&As[kk][64 + tx * 4];
      const f32x4 b0 = *(const f32x4*)&Bs[kk][ty * 4];
      const f32x4 b1 = *(const f32x4*)&Bs[kk][64 + ty * 4];
      float a[8] = {a0[0], a0[1], a0[2], a0[3], a1[0], a1[1], a1[2], a1[3]};
      float bb[8] = {b0[0], b0[1], b0[2], b0[3], b1[0], b1[1], b1[2], b1[3]};
#pragma unroll
      for (int i = 0; i < 8; ++i)
#pragma unroll
        for (int j = 0; j < 8; ++j) c[i][j] = fmaf(a[i], bb[j], c[i][j]);
    }
    __syncthreads();
  }
#pragma unroll
  for (int i = 0; i < 8; ++i) {
    const int m = m0 + ((i >> 2) * 64) + tx * 4 + (i & 3);
    const int bt = m >> 10, n = m & 1023;
#pragma unroll
    for (int j = 0; j < 8; ++j) {
      const int o = o0 + ((j >> 2) * 64) + ty * 4 + (j & 3);
      float val = c[i][j];
      const int bth = bt * 8 + (o >> 5), dh = o & 31;
      const size_t idx = ((size_t)bth * 1024 + n) * 32 + dh;
      if (z == 0) {
        val += qb[o];
        qf[idx] = val;
        __bf16 h = (__bf16)val;
        qh_g[idx] = h;
        ql_g[idx] = (__bf16)(val - (float)h);
      } else if (z == 1) {
        __bf16 h = (__bf16)val;
        kh_g[idx] = h;
        kl_g[idx] = (__bf16)(val - (float)h);
      } else if (z == 2) {
        const size_t tix = ((size_t)bth * 32 + dh) * 1024 + n;
        __bf16 h = (__bf16)val;
        vhT_g[tix] = h;
        vlT_g[tix] = (__bf16)(val - (float)h);
      } else if (z == 3) {
        kloc[idx] = val;
      } else {
        vloc[idx] = val;
      }
    }
  }
}

// ---------------------------------------------------------------------------
// K3: MFMA flash attention, NO LDS staging: B-fragments (K rows, V^T dims)
// are 16B-contiguous per lane -> direct global loads (L2-shared across the
// 16 q-tile blocks per bth). 64-key chunks. l accumulated via all-ones MFMA
// column (oc2) -- rescales with the same alpha as O. No block barriers in
// the main loop; wave-private LDS only for the P C->A layout round-trip.
// ---------------------------------------------------------------------------
#define PSTR 68  // pbuf row stride in floats (64 + 4; 16B-aligned rows)
__device__ __forceinline__ float rmax16(float v) {
  v = fmaxf(v, __shfl_xor(v, 1));
  v = fmaxf(v, __shfl_xor(v, 2));
  v = fmaxf(v, __shfl_xor(v, 4));
  v = fmaxf(v, __shfl_xor(v, 8));
  return v;
}

__global__ __launch_bounds__(256) void attn_kernel(
    const __bf16* __restrict__ qh_g, const __bf16* __restrict__ ql_g,
    const __bf16* __restrict__ kh_g, const __bf16* __restrict__ kl_g,
    const __bf16* __restrict__ vhT_g, const __bf16* __restrict__ vlT_g,
    const float* __restrict__ qf, const float* __restrict__ kloc,
    const float* __restrict__ vloc, float* __restrict__ ctx) {
  __shared__ float pbs[4][16 * PSTR];  // per-wave P round-trip; obuf overlays
  float* obuf = &pbs[0][0];            // 64*36 = 2304 floats (fits in 4352)

  const int qt = blockIdx.x, bth = blockIdx.y;
  const int tid = threadIdx.x;
  const int w = tid >> 6, lane = tid & 63;
  const int col = lane & 15, grp = lane >> 4;
  const int m0 = qt * 64 + w * 16;
  const float SCALE2 = 0.17677669529663687f * 1.4426950408889634f;  // dh^-.5*log2e
  const size_t kvbase = (size_t)bth << 10;
  float* pb = pbs[w];

  bf16x8 onesf;
#pragma unroll
  for (int j = 0; j < 8; ++j) onesf[j] = (__bf16)1.0f;

  // Q A-fragments (hi/lo): m=col, k=8*grp+j
  const bf16x8 qhf = *(const bf16x8*)(qh_g + (kvbase + m0 + col) * 32 + 8 * grp);
  const bf16x8 qlf = *(const bf16x8*)(ql_g + (kvbase + m0 + col) * 32 + 8 * grp);

  f32x4 oc0 = {0.f, 0.f, 0.f, 0.f}, oc1 = {0.f, 0.f, 0.f, 0.f};
  f32x4 oc2 = {0.f, 0.f, 0.f, 0.f};  // sum(p) via ones-column
  float mrow[4] = {-1e30f, -1e30f, -1e30f, -1e30f};

#pragma unroll 1
  for (int ch = 0; ch < 16; ++ch) {
    const int key0 = ch * 64;
    // ---- direct global B-fragment loads (16B contiguous per lane)
    bf16x8 kh[4], kl[4];
#pragma unroll
    for (int t = 0; t < 4; ++t) {
      kh[t] = *(const bf16x8*)(kh_g + (kvbase + key0 + t * 16 + col) * 32 + 8 * grp);
      kl[t] = *(const bf16x8*)(kl_g + (kvbase + key0 + t * 16 + col) * 32 + 8 * grp);
    }
    bf16x8 vh[2][2], vl[2][2];
#pragma unroll
    for (int h = 0; h < 2; ++h)
#pragma unroll
      for (int s = 0; s < 2; ++s) {
        const size_t off = ((size_t)bth * 32 + h * 16 + col) * 1024 + key0 + s * 32 + 8 * grp;
        vh[h][s] = *(const bf16x8*)(vhT_g + off);
        vl[h][s] = *(const bf16x8*)(vlT_g + off);
      }
    // ---- QK^T: four 16-key col tiles, bf16x3
    f32x4 s_[4];
#pragma unroll
    for (int t = 0; t < 4; ++t) {
      f32x4 acc = {0.f, 0.f, 0.f, 0.f};
      acc = __builtin_amdgcn_mfma_f32_16x16x32_bf16(qlf, kh[t], acc, 0, 0, 0);
      acc = __builtin_amdgcn_mfma_f32_16x16x32_bf16(qhf, kl[t], acc, 0, 0, 0);
      acc = __builtin_amdgcn_mfma_f32_16x16x32_bf16(qhf, kh[t], acc, 0, 0, 0);
      s_[t] = acc;
    }
    // ---- online softmax per owned row (row = 4*grp + r)
#pragma unroll
    for (int r = 0; r < 4; ++r) {
      float raw = fmaxf(fmaxf(s_[0][r], s_[1][r]), fmaxf(s_[2][r], s_[3][r]));
      raw = rmax16(raw);
      const float mm = raw * SCALE2;
      const float mn = fmaxf(mrow[r], mm);
      const float al = __builtin_amdgcn_exp2f(mrow[r] - mn);
      mrow[r] = mn;
      oc0[r] *= al;
      oc1[r] *= al;
      oc2[r] *= al;
#pragma unroll
      for (int t = 0; t < 4; ++t) {
        const float p = __builtin_amdgcn_exp2f(fmaf(s_[t][r], SCALE2, -mn));
        pb[(grp * 4 + r) * PSTR + t * 16 + col] = p;
      }
    }
    __builtin_amdgcn_wave_barrier();
    // ---- P: C-layout -> A-layout (wave-private LDS), split hi/lo
    bf16x8 ph[2], pl[2];
#pragma unroll
    for (int s = 0; s < 2; ++s) {
      const f32x4 pa0 = *(const f32x4*)&pb[col * PSTR + s * 32 + 8 * grp];
      const f32x4 pa1 = *(const f32x4*)&pb[col * PSTR + s * 32 + 8 * grp + 4];
#pragma unroll
      for (int j = 0; j < 4; ++j) {
        const __bf16 h0 = (__bf16)pa0[j];
        ph[s][j] = h0;
        pl[s][j] = (__bf16)(pa0[j] - (float)h0);
        const __bf16 h1 = (__bf16)pa1[j];
        ph[s][4 + j] = h1;
        pl[s][4 + j] = (__bf16)(pa1[j] - (float)h1);
      }
    }
    __builtin_amdgcn_wave_barrier();
    // ---- PV + ones-column (l), bf16x3
#pragma unroll
    for (int s = 0; s < 2; ++s) {
      oc0 = __builtin_amdgcn_mfma_f32_16x16x32_bf16(pl[s], vh[0][s], oc0, 0, 0, 0);
      oc0 = __builtin_amdgcn_mfma_f32_16x16x32_bf16(ph[s], vl[0][s], oc0, 0, 0, 0);
      oc0 = __builtin_amdgcn_mfma_f32_16x16x32_bf16(ph[s], vh[0][s], oc0, 0, 0, 0);
      oc1 = __builtin_amdgcn_mfma_f32_16x16x32_bf16(pl[s], vh[1][s], oc1, 0, 0, 0);
      oc1 = __builtin_amdgcn_mfma_f32_16x16x32_bf16(ph[s], vl[1][s], oc1, 0, 0, 0);
      oc1 = __builtin_amdgcn_mfma_f32_16x16x32_bf16(ph[s], vh[1][s], oc1, 0, 0, 0);
      oc2 = __builtin_amdgcn_mfma_f32_16x16x32_bf16(pl[s], onesf, oc2, 0, 0, 0);
      oc2 = __builtin_amdgcn_mfma_f32_16x16x32_bf16(ph[s], onesf, oc2, 0, 0, 0);
    }
  }

  // ---- dump per-query state (O, m, l) to LDS (overlay on pbuf)
  __syncthreads();
#pragma unroll
  for (int r = 0; r < 4; ++r) {
    const int qq = w * 16 + grp * 4 + r;
    obuf[qq * 36 + col] = oc0[r];
    obuf[qq * 36 + 16 + col] = oc1[r];
    if (col == 0) {
      obuf[qq * 36 + 32] = mrow[r];
      obuf[qq * 36 + 33] = oc2[r];
    }
  }
  __syncthreads();

  // ---- local 3x3 pass + finalize: 64 lanes, lane = query (fp32 VALU)
  if (tid < 64) {
    const int qq = tid;
    const int n = qt * 64 + qq;
    float M = obuf[qq * 36 + 32], L = obuf[qq * 36 + 33];
    float A[32];
#pragma unroll
    for (int d = 0; d < 32; ++d) A[d] = obuf[qq * 36 + d];
    float qrf[32];
    {
      const float* qp = qf + (kvbase + n) * 32;
#pragma unroll
      for (int d = 0; d < 32; ++d) qrf[d] = qp[d] * SCALE2;
    }
    const int pi = n >> 5, pj = n & 31;
    float sl[9];
#pragma unroll
    for (int tt = 0; tt < 9; ++tt) {
      const int ni = pi + tt / 3 - 1;
      const int nj = pj + tt % 3 - 1;
      const bool ok = (ni >= 0) && (ni < 32) && (nj >= 0) && (nj < 32);
      float s = -1e30f;
      if (ok) {
        const float* kr = kloc + (kvbase + ni * 32 + nj) * 32;
        float s0 = 0.f, s1 = 0.f, s2 = 0.f, s3 = 0.f;
#pragma unroll
        for (int d = 0; d < 32; d += 4) {
          s0 = fmaf(qrf[d + 0], kr[d + 0], s0);
          s1 = fmaf(qrf[d + 1], kr[d + 1], s1);
          s2 = fmaf(qrf[d + 2], kr[d + 2], s2);
          s3 = fmaf(qrf[d + 3], kr[d + 3], s3);
        }
        s = (s0 + s1) + (s2 + s3);
      }
      sl[tt] = s;
    }
    float tm = sl[0];
#pragma unroll
    for (int tt = 1; tt < 9; ++tt) tm = fmaxf(tm, sl[tt]);
    const float mn = fmaxf(M, tm);
    const float al = __builtin_amdgcn_exp2f(M - mn);
    M = mn;
    L *= al;
#pragma unroll
    for (int d = 0; d < 32; ++d) A[d] *= al;
#pragma unroll
    for (int tt = 0; tt < 9; ++tt) {
      const int ni = pi + tt / 3 - 1;
      const int nj = pj + tt % 3 - 1;
      const bool ok = (ni >= 0) && (ni < 32) && (nj >= 0) && (nj < 32);
      if (ok) {
        const float p = __builtin_amdgcn_exp2f(sl[tt] - mn);
        L += p;
        const float* vr = vloc + (kvbase + ni * 32 + nj) * 32;
#pragma unroll
        for (int d = 0; d < 32; ++d) A[d] = fmaf(p, vr[d], A[d]);
      }
    }
    const float inv = 1.0f / L;
    const int bt = bth >> 3, head = bth & 7;
    float* op = ctx + (((size_t)bt * 1024 + n) * 8 + head) * 32;
#pragma unroll
    for (int f = 0; f < 8; ++f) {
      float4 o;
      o.x = A[f * 4 + 0] * inv;
      o.y = A[f * 4 + 1] * inv;
      o.z = A[f * 4 + 2] * inv;
      o.w = A[f * 4 + 3] * inv;
      ((float4*)op)[f] = o;
    }
  }
}

// ---------------------------------------------------------------------------
// K4: out = ctx(8192x256) @ Wo^T, 128x128 tile, 8x8 micro, fp32.
// Stored as (B, D, T, H*W) with n contiguous. grid (64, 2).
// ---------------------------------------------------------------------------
__global__ __launch_bounds__(256) void outproj_kernel(const float* __restrict__ ctx,
                                                      const float* __restrict__ Wo,
                                                      float* __restrict__ out) {
  __shared__ float As[16][128];
  __shared__ float Bs[16][132];
  const int m0 = blockIdx.x * 128;
  const int o0 = blockIdx.y * 128;
  const int tid = threadIdx.x;
  const int tx = tid & 15, ty = tid >> 4;
  float c[8][8] = {};
#pragma unroll 1
  for (int k0 = 0; k0 < 256; k0 += 16) {
    {  // stage A from row-major ctx: coalesced along k
      const int kb = tid & 15, mb = tid >> 4;
#pragma unroll
      for (int rr = 0; rr < 8; ++rr)
        As[kb][mb + rr * 16] = ctx[(size_t)(m0 + mb + rr * 16) * 256 + k0 + kb];
    }
    {
      const int kb = tid & 15, ob = tid >> 4;
#pragma unroll
      for (int rr = 0; rr < 8; ++rr)
        Bs[kb][ob + rr * 16] = Wo[(size_t)(o0 + ob + rr * 16) * 256 + k0 + kb];
    }
    __syncthreads();
#pragma unroll
    for (int kk = 0; kk < 16; ++kk) {
      const f32x4 a0 = *(const f32x4*)&As[kk][tx * 4];
      const f32x4 a1 = *(const f32x4*)&As[kk][64 + tx * 4];
      const f32x4 b0 = *(const f32x4*)&Bs[kk][ty * 4];
      const f32x4 b1 = *(const f32x4*)&Bs[kk][64 + ty * 4];
      float a[8] = {a0[0], a0[1], a0[2], a0[3], a1[0], a1[1], a1[2], a1[3]};
      float bb[8] = {b0[0], b0[1], b0[2], b0[3], b1[0], b1[1], b1[2], b1[3]};
#pragma unroll
      for (int i = 0; i < 8; ++i)
#pragma unroll
        for (int j = 0; j < 8; ++j) c[i][j] = fmaf(a[i], bb[j], c[i][j]);
    }
    __syncthreads();
  }
#pragma unroll
  for (int i = 0; i < 8; ++i) {
    const int m = m0 + ((i >> 2) * 64) + tx * 4 + (i & 3);
    const int bt = m >> 10, n = m & 1023;
    const int b = bt >> 2, t = bt & 3;
#pragma unroll
    for (int j = 0; j < 8; ++j) {
      const int o = o0 + ((j >> 2) * 64) + ty * 4 + (j & 3);
      out[((size_t)(b * 256 + o) * 4 + t) * 1024 + n] = c[i][j];
    }
  }
}

extern "C" void kernel_launch(void* const* d_in, const int* in_sizes, int n_in,
                              void* d_out, int out_size, void* d_ws, size_t ws_size,
                              hipStream_t stream) {
  const float* x = (const float*)d_in[0];
  const float* gamma = (const float*)d_in[1];
  const float* beta = (const float*)d_in[2];
  const float* Wq = (const float*)d_in[3];
  const float* Wk = (const float*)d_in[4];
  const float* Wv = (const float*)d_in[5];
  const float* Wkl = (const float*)d_in[6];
  const float* Wvl = (const float*)d_in[7];
  const float* Wo = (const float*)d_in[8];
  const float* qb = (const float*)d_in[9];

  float* ws = (float*)d_ws;
  const size_t SZ = (size_t)NROWS * 256;  // 2M elems
  float* xnT = ws;
  float* qf = ws + SZ;
  float* kloc = ws + 2 * SZ;
  float* vloc = ws + 3 * SZ;
  float* ctx = ws + 4 * SZ;
  __bf16* bfb = (__bf16*)(ws + 5 * SZ);
  __bf16* qh = bfb;
  __bf16* ql = bfb + SZ;
  __bf16* kh = bfb + 2 * SZ;
  __bf16* kl = bfb + 3 * SZ;
  __bf16* vhT = bfb + 4 * SZ;
  __bf16* vlT = bfb + 5 * SZ;  // total ws: 20MB fp32 + 24MB bf16 = 44MB

  hipLaunchKernelGGL(ln_kernel, dim3(256), dim3(256), 0, stream, x, gamma, beta, xnT);
  hipLaunchKernelGGL(proj_kernel, dim3(64, 2, 5), dim3(256), 0, stream, xnT, Wq,
                     Wk, Wv, Wkl, Wvl, qb, qf, qh, ql, kh, kl, vhT, vlT, kloc, vloc);
  hipLaunchKernelGGL(attn_kernel, dim3(16, 64), dim3(256), 0, stream, qh, ql, kh,
                     kl, vhT, vlT, qf, kloc, vloc, ctx);
  hipLaunchKernelGGL(outproj_kernel, dim3(64, 2), dim3(256), 0, stream, ctx, Wo,
                     (float*)d_out);
}

// Round 6
// 302.012 us; speedup vs baseline: 1.1171x; 1.1171x over previous
//
#include <hip/hip_runtime.h>

#define NROWS 8192  // BT * N = 8 * 1024

typedef float f32x4 __attribute__((ext_vector_type(4)));
typedef __bf16 bf16x8 __attribute__((ext_vector_type(8)));
typedef __bf16 bf16x4 __attribute__((ext_vector_type(4)));

// ---------------------------------------------------------------------------
// K1: LayerNorm over D=256 + transpose to K-major xnT[d][bt*1024+n]
// ---------------------------------------------------------------------------
__global__ __launch_bounds__(256) void ln_kernel(const float* __restrict__ x,
                                                 const float* __restrict__ gamma,
                                                 const float* __restrict__ beta,
                                                 float* __restrict__ xnT) {
  __shared__ float red[2][8][32];
  const int blk = blockIdx.x;  // 256 = bt(8) x nchunk(32)
  const int bt = blk >> 5;
  const int b = bt >> 2, t = bt & 3;
  const int n0 = (blk & 31) << 5;
  const int part = threadIdx.x >> 5, r = threadIdx.x & 31;
  const int n = n0 + r;
  const float* xp = x + ((size_t)(b * 256) * 4 + t) * 1024 + n;  // d stride 4096
  float sum = 0.f, sumsq = 0.f;
#pragma unroll 8
  for (int dd = 0; dd < 32; ++dd) {
    float vv = xp[(size_t)(part * 32 + dd) * 4096];
    sum += vv;
    sumsq += vv * vv;
  }
  red[0][part][r] = sum;
  red[1][part][r] = sumsq;
  __syncthreads();
  float s1 = 0.f, s2 = 0.f;
#pragma unroll
  for (int p = 0; p < 8; ++p) {
    s1 += red[0][p][r];
    s2 += red[1][p][r];
  }
  const float mu = s1 * (1.0f / 256.0f);
  const float var = s2 * (1.0f / 256.0f) - mu * mu;
  const float rstd = rsqrtf(var + 1e-6f);
  float* outp = xnT + (size_t)bt * 1024 + n;
#pragma unroll 8
  for (int dd = 0; dd < 32; ++dd) {
    const int d = part * 32 + dd;
    float vv = xp[(size_t)d * 4096];
    outp[(size_t)d * NROWS] = (vv - mu) * rstd * gamma[d] + beta[d];
  }
}

// ---------------------------------------------------------------------------
// K2: 5 projections, 128x128 tile, 8x8 micro. MICRO-TILE SWAPPED:
// tx (lane-fast) -> output channel o, ty -> token m. Epilogue stores are
// float4 / bf16x4 with lane-contiguous addresses (coalesced).
// ---------------------------------------------------------------------------
__global__ __launch_bounds__(256) void proj_kernel(
    const float* __restrict__ xnT,
    const float* __restrict__ Wq, const float* __restrict__ Wk,
    const float* __restrict__ Wv, const float* __restrict__ Wkl,
    const float* __restrict__ Wvl, const float* __restrict__ qb,
    float* __restrict__ qf, __bf16* __restrict__ qh_g, __bf16* __restrict__ ql_g,
    __bf16* __restrict__ kh_g, __bf16* __restrict__ kl_g,
    __bf16* __restrict__ vhT_g, __bf16* __restrict__ vlT_g,
    float* __restrict__ kloc, float* __restrict__ vloc) {
  __shared__ float As[16][128];
  __shared__ float Bs[16][132];
  const int z = blockIdx.z;
  const float* Wm = (z == 0) ? Wq : (z == 1) ? Wk : (z == 2) ? Wv : (z == 3) ? Wkl : Wvl;
  const int m0 = blockIdx.x * 128;
  const int o0 = blockIdx.y * 128;
  const int tid = threadIdx.x;
  const int tx = tid & 15, ty = tid >> 4;
  float c[8][8] = {};  // c[o-idx][m-idx]
#pragma unroll 1
  for (int k0 = 0; k0 < 256; k0 += 16) {
    {  // stage A: coalesced along m
      const int m = tid & 127, kq = tid >> 7;
#pragma unroll
      for (int rr = 0; rr < 8; ++rr)
        As[kq + rr * 2][m] = xnT[(size_t)(k0 + kq + rr * 2) * NROWS + m0 + m];
    }
    {  // stage B: coalesced along k
      const int kb = tid & 15, ob = tid >> 4;
#pragma unroll
      for (int rr = 0; rr < 8; ++rr)
        Bs[kb][ob + rr * 16] = Wm[(size_t)(o0 + ob + rr * 16) * 256 + k0 + kb];
    }
    __syncthreads();
#pragma unroll
    for (int kk = 0; kk < 16; ++kk) {
      const f32x4 b0 = *(const f32x4*)&Bs[kk][tx * 4];
      const f32x4 b1 = *(const f32x4*)&Bs[kk][64 + tx * 4];
      const f32x4 a0 = *(const f32x4*)&As[kk][ty * 4];
      const f32x4 a1 = *(const f32x4*)&As[kk][64 + ty * 4];
      float ov[8] = {b0[0], b0[1], b0[2], b0[3], b1[0], b1[1], b1[2], b1[3]};
      float mv[8] = {a0[0], a0[1], a0[2], a0[3], a1[0], a1[1], a1[2], a1[3]};
#pragma unroll
      for (int i = 0; i < 8; ++i)
#pragma unroll
        for (int j = 0; j < 8; ++j) c[i][j] = fmaf(ov[i], mv[j], c[i][j]);
    }
    __syncthreads();
  }
  if (z == 2) {
    // v transposed (bth, dh, n): vectorize over 4 consecutive tokens
#pragma unroll
    for (int i = 0; i < 8; ++i) {
      const int o = o0 + (i >> 2) * 64 + tx * 4 + (i & 3);
      const int head = o >> 5, dh = o & 31;
#pragma unroll
      for (int jg = 0; jg < 2; ++jg) {
        const int m = m0 + jg * 64 + ty * 4;
        const int bt = m >> 10, ntok = m & 1023;
        const int bth = bt * 8 + head;
        bf16x4 hv, lv;
#pragma unroll
        for (int jl = 0; jl < 4; ++jl) {
          const float val = c[i][jg * 4 + jl];
          const __bf16 h = (__bf16)val;
          hv[jl] = h;
          lv[jl] = (__bf16)(val - (float)h);
        }
        const size_t tix = ((size_t)bth * 32 + dh) * 1024 + ntok;
        *(bf16x4*)(vhT_g + tix) = hv;
        *(bf16x4*)(vlT_g + tix) = lv;
      }
    }
  } else {
#pragma unroll
    for (int ig = 0; ig < 2; ++ig) {
      const int ob = o0 + ig * 64 + tx * 4;  // 4 consecutive o, within one head
      const int head = ob >> 5, dh = ob & 31;
      float4 qb4 = make_float4(0.f, 0.f, 0.f, 0.f);
      if (z == 0) qb4 = *(const float4*)&qb[ob];
#pragma unroll
      for (int j = 0; j < 8; ++j) {
        const int m = m0 + (j >> 2) * 64 + ty * 4 + (j & 3);
        const int bt = m >> 10, ntok = m & 1023;
        const size_t idx = (((size_t)(bt * 8 + head)) * 1024 + ntok) * 32 + dh;
        float v0 = c[ig * 4 + 0][j], v1 = c[ig * 4 + 1][j];
        float v2 = c[ig * 4 + 2][j], v3 = c[ig * 4 + 3][j];
        if (z == 0) { v0 += qb4.x; v1 += qb4.y; v2 += qb4.z; v3 += qb4.w; }
        if (z <= 1) {
          bf16x4 hv, lv;
          hv[0] = (__bf16)v0; lv[0] = (__bf16)(v0 - (float)hv[0]);
          hv[1] = (__bf16)v1; lv[1] = (__bf16)(v1 - (float)hv[1]);
          hv[2] = (__bf16)v2; lv[2] = (__bf16)(v2 - (float)hv[2]);
          hv[3] = (__bf16)v3; lv[3] = (__bf16)(v3 - (float)hv[3]);
          if (z == 0) {
            *(float4*)(qf + idx) = make_float4(v0, v1, v2, v3);
            *(bf16x4*)(qh_g + idx) = hv;
            *(bf16x4*)(ql_g + idx) = lv;
          } else {
            *(bf16x4*)(kh_g + idx) = hv;
            *(bf16x4*)(kl_g + idx) = lv;
          }
        } else {
          const float4 f4 = make_float4(v0, v1, v2, v3);
          if (z == 3) *(float4*)(kloc + idx) = f4;
          else *(float4*)(vloc + idx) = f4;
        }
      }
    }
  }
}

// ---------------------------------------------------------------------------
// K3: MFMA flash attention. Grid (bth=64, qt=16): bth is the fast blockIdx
// dim -> the 16 q-tile blocks of one bth land on ONE XCD (round-robin id%8)
// -> K/V hit that XCD's L2. K fragments register-double-buffered one chunk
// ahead (unroll-2 parity); V issued at iteration top, used at the end.
// ---------------------------------------------------------------------------
#define PSTR 68
__device__ __forceinline__ float rmax16(float v) {
  v = fmaxf(v, __shfl_xor(v, 1));
  v = fmaxf(v, __shfl_xor(v, 2));
  v = fmaxf(v, __shfl_xor(v, 4));
  v = fmaxf(v, __shfl_xor(v, 8));
  return v;
}

__global__ __launch_bounds__(256) void attn_kernel(
    const __bf16* __restrict__ qh_g, const __bf16* __restrict__ ql_g,
    const __bf16* __restrict__ kh_g, const __bf16* __restrict__ kl_g,
    const __bf16* __restrict__ vhT_g, const __bf16* __restrict__ vlT_g,
    const float* __restrict__ qf, const float* __restrict__ kloc,
    const float* __restrict__ vloc, float* __restrict__ ctx) {
  __shared__ float pbs[4][16 * PSTR];
  float* obuf = &pbs[0][0];

  const int bth = blockIdx.x, qt = blockIdx.y;
  const int tid = threadIdx.x;
  const int w = tid >> 6, lane = tid & 63;
  const int col = lane & 15, grp = lane >> 4;
  const int m0 = qt * 64 + w * 16;
  const float SCALE2 = 0.17677669529663687f * 1.4426950408889634f;  // dh^-.5*log2e
  const size_t kvbase = (size_t)bth << 10;
  float* pb = pbs[w];

  bf16x8 onesf;
#pragma unroll
  for (int j = 0; j < 8; ++j) onesf[j] = (__bf16)1.0f;

  const bf16x8 qhf = *(const bf16x8*)(qh_g + (kvbase + m0 + col) * 32 + 8 * grp);
  const bf16x8 qlf = *(const bf16x8*)(ql_g + (kvbase + m0 + col) * 32 + 8 * grp);

  f32x4 oc0 = {0.f, 0.f, 0.f, 0.f}, oc1 = {0.f, 0.f, 0.f, 0.f};
  f32x4 oc2 = {0.f, 0.f, 0.f, 0.f};
  float mrow[4] = {-1e30f, -1e30f, -1e30f, -1e30f};

  // K fragment double-buffer (parity-indexed; unroll 2 makes indices const)
  bf16x8 khb[2][4], klb[2][4];
#pragma unroll
  for (int t = 0; t < 4; ++t) {
    khb[0][t] = *(const bf16x8*)(kh_g + (kvbase + t * 16 + col) * 32 + 8 * grp);
    klb[0][t] = *(const bf16x8*)(kl_g + (kvbase + t * 16 + col) * 32 + 8 * grp);
  }

#pragma unroll 2
  for (int ch = 0; ch < 16; ++ch) {
    const int cur = ch & 1, nxt = cur ^ 1;
    const int key0 = ch * 64;
    // ---- V loads for this chunk (issued early, used at the end)
    bf16x8 vh[2][2], vl[2][2];
#pragma unroll
    for (int h = 0; h < 2; ++h)
#pragma unroll
      for (int s = 0; s < 2; ++s) {
        const size_t off = ((size_t)bth * 32 + h * 16 + col) * 1024 + key0 + s * 32 + 8 * grp;
        vh[h][s] = *(const bf16x8*)(vhT_g + off);
        vl[h][s] = *(const bf16x8*)(vlT_g + off);
      }
    // ---- prefetch next chunk's K fragments
    if (ch < 15) {
#pragma unroll
      for (int t = 0; t < 4; ++t) {
        khb[nxt][t] = *(const bf16x8*)(kh_g + (kvbase + key0 + 64 + t * 16 + col) * 32 + 8 * grp);
        klb[nxt][t] = *(const bf16x8*)(kl_g + (kvbase + key0 + 64 + t * 16 + col) * 32 + 8 * grp);
      }
    }
    // ---- QK^T: four 16-key col tiles, bf16x3
    f32x4 s_[4];
#pragma unroll
    for (int t = 0; t < 4; ++t) {
      f32x4 acc = {0.f, 0.f, 0.f, 0.f};
      acc = __builtin_amdgcn_mfma_f32_16x16x32_bf16(qlf, khb[cur][t], acc, 0, 0, 0);
      acc = __builtin_amdgcn_mfma_f32_16x16x32_bf16(qhf, klb[cur][t], acc, 0, 0, 0);
      acc = __builtin_amdgcn_mfma_f32_16x16x32_bf16(qhf, khb[cur][t], acc, 0, 0, 0);
      s_[t] = acc;
    }
    // ---- online softmax per owned row (row = 4*grp + r)
#pragma unroll
    for (int r = 0; r < 4; ++r) {
      float raw = fmaxf(fmaxf(s_[0][r], s_[1][r]), fmaxf(s_[2][r], s_[3][r]));
      raw = rmax16(raw);
      const float mm = raw * SCALE2;
      const float mn = fmaxf(mrow[r], mm);
      const float al = __builtin_amdgcn_exp2f(mrow[r] - mn);
      mrow[r] = mn;
      oc0[r] *= al;
      oc1[r] *= al;
      oc2[r] *= al;
#pragma unroll
      for (int t = 0; t < 4; ++t) {
        const float p = __builtin_amdgcn_exp2f(fmaf(s_[t][r], SCALE2, -mn));
        pb[(grp * 4 + r) * PSTR + t * 16 + col] = p;
      }
    }
    __builtin_amdgcn_wave_barrier();
    // ---- P: C-layout -> A-layout (wave-private LDS), split hi/lo
    bf16x8 ph[2], pl[2];
#pragma unroll
    for (int s = 0; s < 2; ++s) {
      const f32x4 pa0 = *(const f32x4*)&pb[col * PSTR + s * 32 + 8 * grp];
      const f32x4 pa1 = *(const f32x4*)&pb[col * PSTR + s * 32 + 8 * grp + 4];
#pragma unroll
      for (int j = 0; j < 4; ++j) {
        const __bf16 h0 = (__bf16)pa0[j];
        ph[s][j] = h0;
        pl[s][j] = (__bf16)(pa0[j] - (float)h0);
        const __bf16 h1 = (__bf16)pa1[j];
        ph[s][4 + j] = h1;
        pl[s][4 + j] = (__bf16)(pa1[j] - (float)h1);
      }
    }
    __builtin_amdgcn_wave_barrier();
    // ---- PV + ones-column (l), bf16x3
#pragma unroll
    for (int s = 0; s < 2; ++s) {
      oc0 = __builtin_amdgcn_mfma_f32_16x16x32_bf16(pl[s], vh[0][s], oc0, 0, 0, 0);
      oc0 = __builtin_amdgcn_mfma_f32_16x16x32_bf16(ph[s], vl[0][s], oc0, 0, 0, 0);
      oc0 = __builtin_amdgcn_mfma_f32_16x16x32_bf16(ph[s], vh[0][s], oc0, 0, 0, 0);
      oc1 = __builtin_amdgcn_mfma_f32_16x16x32_bf16(pl[s], vh[1][s], oc1, 0, 0, 0);
      oc1 = __builtin_amdgcn_mfma_f32_16x16x32_bf16(ph[s], vl[1][s], oc1, 0, 0, 0);
      oc1 = __builtin_amdgcn_mfma_f32_16x16x32_bf16(ph[s], vh[1][s], oc1, 0, 0, 0);
      oc2 = __builtin_amdgcn_mfma_f32_16x16x32_bf16(pl[s], onesf, oc2, 0, 0, 0);
      oc2 = __builtin_amdgcn_mfma_f32_16x16x32_bf16(ph[s], onesf, oc2, 0, 0, 0);
    }
  }

  // ---- dump per-query state (O, m, l) to LDS (overlay on pbuf)
  __syncthreads();
#pragma unroll
  for (int r = 0; r < 4; ++r) {
    const int qq = w * 16 + grp * 4 + r;
    obuf[qq * 36 + col] = oc0[r];
    obuf[qq * 36 + 16 + col] = oc1[r];
    if (col == 0) {
      obuf[qq * 36 + 32] = mrow[r];
      obuf[qq * 36 + 33] = oc2[r];
    }
  }
  __syncthreads();

  // ---- local 3x3 pass + finalize: 64 lanes, lane = query (fp32 VALU)
  if (tid < 64) {
    const int qq = tid;
    const int n = qt * 64 + qq;
    float M = obuf[qq * 36 + 32], L = obuf[qq * 36 + 33];
    float A[32];
#pragma unroll
    for (int d = 0; d < 32; ++d) A[d] = obuf[qq * 36 + d];
    float qrf[32];
    {
      const float* qp = qf + (kvbase + n) * 32;
#pragma unroll
      for (int d = 0; d < 32; ++d) qrf[d] = qp[d] * SCALE2;
    }
    const int pi = n >> 5, pj = n & 31;
    float sl[9];
#pragma unroll
    for (int tt = 0; tt < 9; ++tt) {
      const int ni = pi + tt / 3 - 1;
      const int nj = pj + tt % 3 - 1;
      const bool ok = (ni >= 0) && (ni < 32) && (nj >= 0) && (nj < 32);
      float s = -1e30f;
      if (ok) {
        const float* kr = kloc + (kvbase + ni * 32 + nj) * 32;
        float s0 = 0.f, s1 = 0.f, s2 = 0.f, s3 = 0.f;
#pragma unroll
        for (int d = 0; d < 32; d += 4) {
          s0 = fmaf(qrf[d + 0], kr[d + 0], s0);
          s1 = fmaf(qrf[d + 1], kr[d + 1], s1);
          s2 = fmaf(qrf[d + 2], kr[d + 2], s2);
          s3 = fmaf(qrf[d + 3], kr[d + 3], s3);
        }
        s = (s0 + s1) + (s2 + s3);
      }
      sl[tt] = s;
    }
    float tm = sl[0];
#pragma unroll
    for (int tt = 1; tt < 9; ++tt) tm = fmaxf(tm, sl[tt]);
    const float mn = fmaxf(M, tm);
    const float al = __builtin_amdgcn_exp2f(M - mn);
    M = mn;
    L *= al;
#pragma unroll
    for (int d = 0; d < 32; ++d) A[d] *= al;
#pragma unroll
    for (int tt = 0; tt < 9; ++tt) {
      const int ni = pi + tt / 3 - 1;
      const int nj = pj + tt % 3 - 1;
      const bool ok = (ni >= 0) && (ni < 32) && (nj >= 0) && (nj < 32);
      if (ok) {
        const float p = __builtin_amdgcn_exp2f(sl[tt] - mn);
        L += p;
        const float* vr = vloc + (kvbase + ni * 32 + nj) * 32;
#pragma unroll
        for (int d = 0; d < 32; ++d) A[d] = fmaf(p, vr[d], A[d]);
      }
    }
    const float inv = 1.0f / L;
    const int bt = bth >> 3, head = bth & 7;
    float* op = ctx + (((size_t)bt * 1024 + n) * 8 + head) * 32;
#pragma unroll
    for (int f = 0; f < 8; ++f) {
      float4 o;
      o.x = A[f * 4 + 0] * inv;
      o.y = A[f * 4 + 1] * inv;
      o.z = A[f * 4 + 2] * inv;
      o.w = A[f * 4 + 3] * inv;
      ((float4*)op)[f] = o;
    }
  }
}

// ---------------------------------------------------------------------------
// K4: out = ctx(8192x256) @ Wo^T, 128x128 tile, 8x8 micro, fp32.
// Epilogue: float4 stores over 4 consecutive tokens (out is n-contiguous).
// ---------------------------------------------------------------------------
__global__ __launch_bounds__(256) void outproj_kernel(const float* __restrict__ ctx,
                                                      const float* __restrict__ Wo,
                                                      float* __restrict__ out) {
  __shared__ float As[16][128];
  __shared__ float Bs[16][132];
  const int m0 = blockIdx.x * 128;
  const int o0 = blockIdx.y * 128;
  const int tid = threadIdx.x;
  const int tx = tid & 15, ty = tid >> 4;
  float c[8][8] = {};  // c[m-idx][o-idx]
#pragma unroll 1
  for (int k0 = 0; k0 < 256; k0 += 16) {
    {
      const int kb = tid & 15, mb = tid >> 4;
#pragma unroll
      for (int rr = 0; rr < 8; ++rr)
        As[kb][mb + rr * 16] = ctx[(size_t)(m0 + mb + rr * 16) * 256 + k0 + kb];
    }
    {
      const int kb = tid & 15, ob = tid >> 4;
#pragma unroll
      for (int rr = 0; rr < 8; ++rr)
        Bs[kb][ob + rr * 16] = Wo[(size_t)(o0 + ob + rr * 16) * 256 + k0 + kb];
    }
    __syncthreads();
#pragma unroll
    for (int kk = 0; kk < 16; ++kk) {
      const f32x4 a0 = *(const f32x4*)&As[kk][tx * 4];
      const f32x4 a1 = *(const f32x4*)&As[kk][64 + tx * 4];
      const f32x4 b0 = *(const f32x4*)&Bs[kk][ty * 4];
      const f32x4 b1 = *(const f32x4*)&Bs[kk][64 + ty * 4];
      float a[8] = {a0[0], a0[1], a0[2], a0[3], a1[0], a1[1], a1[2], a1[3]};
      float bb[8] = {b0[0], b0[1], b0[2], b0[3], b1[0], b1[1], b1[2], b1[3]};
#pragma unroll
      for (int i = 0; i < 8; ++i)
#pragma unroll
        for (int j = 0; j < 8; ++j) c[i][j] = fmaf(a[i], bb[j], c[i][j]);
    }
    __syncthreads();
  }
#pragma unroll
  for (int ig = 0; ig < 2; ++ig) {
    const int m = m0 + ig * 64 + tx * 4;  // 4 consecutive tokens
    const int bt = m >> 10, ntok = m & 1023;
    const int b = bt >> 2, t = bt & 3;
#pragma unroll
    for (int j = 0; j < 8; ++j) {
      const int o = o0 + (j >> 2) * 64 + ty * 4 + (j & 3);
      const float4 f4 = make_float4(c[ig * 4 + 0][j], c[ig * 4 + 1][j],
                                    c[ig * 4 + 2][j], c[ig * 4 + 3][j]);
      *(float4*)&out[((size_t)(b * 256 + o) * 4 + t) * 1024 + ntok] = f4;
    }
  }
}

extern "C" void kernel_launch(void* const* d_in, const int* in_sizes, int n_in,
                              void* d_out, int out_size, void* d_ws, size_t ws_size,
                              hipStream_t stream) {
  const float* x = (const float*)d_in[0];
  const float* gamma = (const float*)d_in[1];
  const float* beta = (const float*)d_in[2];
  const float* Wq = (const float*)d_in[3];
  const float* Wk = (const float*)d_in[4];
  const float* Wv = (const float*)d_in[5];
  const float* Wkl = (const float*)d_in[6];
  const float* Wvl = (const float*)d_in[7];
  const float* Wo = (const float*)d_in[8];
  const float* qb = (const float*)d_in[9];

  float* ws = (float*)d_ws;
  const size_t SZ = (size_t)NROWS * 256;  // 2M elems
  float* xnT = ws;
  float* qf = ws + SZ;
  float* kloc = ws + 2 * SZ;
  float* vloc = ws + 3 * SZ;
  float* ctx = ws + 4 * SZ;
  __bf16* bfb = (__bf16*)(ws + 5 * SZ);
  __bf16* qh = bfb;
  __bf16* ql = bfb + SZ;
  __bf16* kh = bfb + 2 * SZ;
  __bf16* kl = bfb + 3 * SZ;
  __bf16* vhT = bfb + 4 * SZ;
  __bf16* vlT = bfb + 5 * SZ;

  hipLaunchKernelGGL(ln_kernel, dim3(256), dim3(256), 0, stream, x, gamma, beta, xnT);
  hipLaunchKernelGGL(proj_kernel, dim3(64, 2, 5), dim3(256), 0, stream, xnT, Wq,
                     Wk, Wv, Wkl, Wvl, qb, qf, qh, ql, kh, kl, vhT, vlT, kloc, vloc);
  hipLaunchKernelGGL(attn_kernel, dim3(64, 16), dim3(256), 0, stream, qh, ql, kh,
                     kl, vhT, vlT, qf, kloc, vloc, ctx);
  hipLaunchKernelGGL(outproj_kernel, dim3(64, 2), dim3(256), 0, stream, ctx, Wo,
                     (float*)d_out);
}

// Round 7
// 251.588 us; speedup vs baseline: 1.3410x; 1.2004x over previous
//
#include <hip/hip_runtime.h>

#define NROWS 8192  // BT * N = 8 * 1024

typedef float f32x4 __attribute__((ext_vector_type(4)));
typedef __bf16 bf16x8 __attribute__((ext_vector_type(8)));
typedef __bf16 bf16x4 __attribute__((ext_vector_type(4)));

// ---------------------------------------------------------------------------
// K1: LayerNorm over D=256. Output: ROW-MAJOR bf16 hi/lo pair xn_h/xn_l
// [token=bt*1024+n][d] -- the A operand for the MFMA projection GEMMs.
// ---------------------------------------------------------------------------
__global__ __launch_bounds__(256) void ln_kernel(const float* __restrict__ x,
                                                 const float* __restrict__ gamma,
                                                 const float* __restrict__ beta,
                                                 __bf16* __restrict__ xnh,
                                                 __bf16* __restrict__ xnl) {
  __shared__ float red[2][8][32];
  const int blk = blockIdx.x;  // 256 = bt(8) x nchunk(32)
  const int bt = blk >> 5;
  const int b = bt >> 2, t = bt & 3;
  const int n0 = (blk & 31) << 5;
  const int part = threadIdx.x >> 5, r = threadIdx.x & 31;
  const int n = n0 + r;
  const float* xp = x + ((size_t)(b * 256) * 4 + t) * 1024 + n;  // d stride 4096
  float sum = 0.f, sumsq = 0.f;
#pragma unroll 8
  for (int dd = 0; dd < 32; ++dd) {
    float vv = xp[(size_t)(part * 32 + dd) * 4096];
    sum += vv;
    sumsq += vv * vv;
  }
  red[0][part][r] = sum;
  red[1][part][r] = sumsq;
  __syncthreads();
  float s1 = 0.f, s2 = 0.f;
#pragma unroll
  for (int p = 0; p < 8; ++p) {
    s1 += red[0][p][r];
    s2 += red[1][p][r];
  }
  const float mu = s1 * (1.0f / 256.0f);
  const float var = s2 * (1.0f / 256.0f) - mu * mu;
  const float rstd = rsqrtf(var + 1e-6f);
  const size_t row = (size_t)bt * 1024 + n;
  __bf16 hbuf[32], lbuf[32];
#pragma unroll 8
  for (int dd = 0; dd < 32; ++dd) {
    const int d = part * 32 + dd;
    float vv = xp[(size_t)d * 4096];
    const float val = (vv - mu) * rstd * gamma[d] + beta[d];
    const __bf16 h = (__bf16)val;
    hbuf[dd] = h;
    lbuf[dd] = (__bf16)(val - (float)h);
  }
  __bf16* oh = xnh + row * 256 + part * 32;
  __bf16* ol = xnl + row * 256 + part * 32;
#pragma unroll
  for (int f = 0; f < 4; ++f) {
    *(bf16x8*)(oh + f * 8) = *(bf16x8*)&hbuf[f * 8];
    *(bf16x8*)(ol + f * 8) = *(bf16x8*)&lbuf[f * 8];
  }
}

// ---------------------------------------------------------------------------
// K2: 5 projections via bf16x3 MFMA. Tile 128x128, BK=32, 4 waves x (64x64).
// A = xn (bf16 h/l, row-major); B = W fp32 split hi/lo during LDS staging.
// C[m][o] = sum_k A[m][k] * B[o][k]; C layout: col=lane&15, row=4*grp+reg.
// ---------------------------------------------------------------------------
#define ASTR 40  // LDS tile row stride in bf16 (32 + 8 pad)
__global__ __launch_bounds__(256) void proj_kernel(
    const __bf16* __restrict__ xnh, const __bf16* __restrict__ xnl,
    const float* __restrict__ Wq, const float* __restrict__ Wk,
    const float* __restrict__ Wv, const float* __restrict__ Wkl,
    const float* __restrict__ Wvl, const float* __restrict__ qb,
    float* __restrict__ qf, __bf16* __restrict__ qh_g, __bf16* __restrict__ ql_g,
    __bf16* __restrict__ kh_g, __bf16* __restrict__ kl_g,
    __bf16* __restrict__ vhT_g, __bf16* __restrict__ vlT_g,
    float* __restrict__ kloc, float* __restrict__ vloc) {
  __shared__ __bf16 Ah[128 * ASTR], Al[128 * ASTR];
  __shared__ __bf16 Bh[128 * ASTR], Bl[128 * ASTR];
  const int z = blockIdx.z;
  const float* Wm = (z == 0) ? Wq : (z == 1) ? Wk : (z == 2) ? Wv : (z == 3) ? Wkl : Wvl;
  const int m0 = blockIdx.x * 128;
  const int o0 = blockIdx.y * 128;
  const int tid = threadIdx.x;
  const int w = tid >> 6, lane = tid & 63;
  const int col = lane & 15, grp = lane >> 4;
  const int mq = (w & 1) * 64, nq = (w >> 1) * 64;
  f32x4 acc[4][4];
#pragma unroll
  for (int i = 0; i < 4; ++i)
#pragma unroll
    for (int j = 0; j < 4; ++j) acc[i][j] = (f32x4){0.f, 0.f, 0.f, 0.f};

#pragma unroll 1
  for (int k0 = 0; k0 < 256; k0 += 32) {
    {  // stage A (bf16 h/l, already split): lane-fast along k, full granules
      const int sg = tid & 3;
#pragma unroll
      for (int p = 0; p < 2; ++p) {
        const int m = p * 64 + (tid >> 2);
        const size_t src = (size_t)(m0 + m) * 256 + k0 + sg * 8;
        *(bf16x8*)&Ah[m * ASTR + sg * 8] = *(const bf16x8*)(xnh + src);
        *(bf16x8*)&Al[m * ASTR + sg * 8] = *(const bf16x8*)(xnl + src);
      }
    }
    {  // stage B (fp32 -> split hi/lo)
      const int sg = tid & 7;
#pragma unroll
      for (int p = 0; p < 4; ++p) {
        const int o = p * 32 + (tid >> 3);
        const float4 f = *(const float4*)(Wm + (size_t)(o0 + o) * 256 + k0 + sg * 4);
        bf16x4 h, l;
        h[0] = (__bf16)f.x; l[0] = (__bf16)(f.x - (float)h[0]);
        h[1] = (__bf16)f.y; l[1] = (__bf16)(f.y - (float)h[1]);
        h[2] = (__bf16)f.z; l[2] = (__bf16)(f.z - (float)h[2]);
        h[3] = (__bf16)f.w; l[3] = (__bf16)(f.w - (float)h[3]);
        *(bf16x4*)&Bh[o * ASTR + sg * 4] = h;
        *(bf16x4*)&Bl[o * ASTR + sg * 4] = l;
      }
    }
    __syncthreads();
    bf16x8 ah[4], al[4], bh[4], bl[4];
#pragma unroll
    for (int mi = 0; mi < 4; ++mi) {
      ah[mi] = *(const bf16x8*)&Ah[(mq + mi * 16 + col) * ASTR + 8 * grp];
      al[mi] = *(const bf16x8*)&Al[(mq + mi * 16 + col) * ASTR + 8 * grp];
    }
#pragma unroll
    for (int ni = 0; ni < 4; ++ni) {
      bh[ni] = *(const bf16x8*)&Bh[(nq + ni * 16 + col) * ASTR + 8 * grp];
      bl[ni] = *(const bf16x8*)&Bl[(nq + ni * 16 + col) * ASTR + 8 * grp];
    }
#pragma unroll
    for (int mi = 0; mi < 4; ++mi)
#pragma unroll
      for (int ni = 0; ni < 4; ++ni) {
        acc[mi][ni] = __builtin_amdgcn_mfma_f32_16x16x32_bf16(al[mi], bh[ni], acc[mi][ni], 0, 0, 0);
        acc[mi][ni] = __builtin_amdgcn_mfma_f32_16x16x32_bf16(ah[mi], bl[ni], acc[mi][ni], 0, 0, 0);
        acc[mi][ni] = __builtin_amdgcn_mfma_f32_16x16x32_bf16(ah[mi], bh[ni], acc[mi][ni], 0, 0, 0);
      }
    __syncthreads();
  }
  // epilogue: token m = m0+mq+mi*16+grp*4+r, out o = o0+nq+ni*16+col
#pragma unroll
  for (int mi = 0; mi < 4; ++mi) {
    const int mb = m0 + mq + mi * 16 + grp * 4;  // 4-aligned, +r stays in same bt
    const int bt = mb >> 10;
    const int nb = mb & 1023;
#pragma unroll
    for (int ni = 0; ni < 4; ++ni) {
      const int o = o0 + nq + ni * 16 + col;
      const int head = o >> 5, dh = o & 31;
      const int bth = bt * 8 + head;
      if (z == 2) {
        bf16x4 hv, lv;
#pragma unroll
        for (int r = 0; r < 4; ++r) {
          const float val = acc[mi][ni][r];
          const __bf16 h = (__bf16)val;
          hv[r] = h;
          lv[r] = (__bf16)(val - (float)h);
        }
        const size_t tix = ((size_t)bth * 32 + dh) * 1024 + nb;
        *(bf16x4*)(vhT_g + tix) = hv;
        *(bf16x4*)(vlT_g + tix) = lv;
      } else if (z <= 1) {
        const float qbo = (z == 0) ? qb[o] : 0.f;
#pragma unroll
        for (int r = 0; r < 4; ++r) {
          const float val = acc[mi][ni][r] + qbo;
          const size_t idx = ((size_t)bth * 1024 + nb + r) * 32 + dh;
          const __bf16 h = (__bf16)val;
          if (z == 0) {
            qf[idx] = val;
            qh_g[idx] = h;
            ql_g[idx] = (__bf16)(val - (float)h);
          } else {
            kh_g[idx] = h;
            kl_g[idx] = (__bf16)(val - (float)h);
          }
        }
      } else {
        float* dst = (z == 3) ? kloc : vloc;
#pragma unroll
        for (int r = 0; r < 4; ++r)
          dst[((size_t)bth * 1024 + nb + r) * 32 + dh] = acc[mi][ni][r];
      }
    }
  }
}

// ---------------------------------------------------------------------------
// K3: MFMA flash attention -- UNCHANGED from round 6 (XCD swizzle + K dbuf).
// ---------------------------------------------------------------------------
#define PSTR 68
__device__ __forceinline__ float rmax16(float v) {
  v = fmaxf(v, __shfl_xor(v, 1));
  v = fmaxf(v, __shfl_xor(v, 2));
  v = fmaxf(v, __shfl_xor(v, 4));
  v = fmaxf(v, __shfl_xor(v, 8));
  return v;
}

__global__ __launch_bounds__(256) void attn_kernel(
    const __bf16* __restrict__ qh_g, const __bf16* __restrict__ ql_g,
    const __bf16* __restrict__ kh_g, const __bf16* __restrict__ kl_g,
    const __bf16* __restrict__ vhT_g, const __bf16* __restrict__ vlT_g,
    const float* __restrict__ qf, const float* __restrict__ kloc,
    const float* __restrict__ vloc, float* __restrict__ ctx) {
  __shared__ float pbs[4][16 * PSTR];
  float* obuf = &pbs[0][0];

  const int bth = blockIdx.x, qt = blockIdx.y;
  const int tid = threadIdx.x;
  const int w = tid >> 6, lane = tid & 63;
  const int col = lane & 15, grp = lane >> 4;
  const int m0 = qt * 64 + w * 16;
  const float SCALE2 = 0.17677669529663687f * 1.4426950408889634f;  // dh^-.5*log2e
  const size_t kvbase = (size_t)bth << 10;
  float* pb = pbs[w];

  bf16x8 onesf;
#pragma unroll
  for (int j = 0; j < 8; ++j) onesf[j] = (__bf16)1.0f;

  const bf16x8 qhf = *(const bf16x8*)(qh_g + (kvbase + m0 + col) * 32 + 8 * grp);
  const bf16x8 qlf = *(const bf16x8*)(ql_g + (kvbase + m0 + col) * 32 + 8 * grp);

  f32x4 oc0 = {0.f, 0.f, 0.f, 0.f}, oc1 = {0.f, 0.f, 0.f, 0.f};
  f32x4 oc2 = {0.f, 0.f, 0.f, 0.f};
  float mrow[4] = {-1e30f, -1e30f, -1e30f, -1e30f};

  bf16x8 khb[2][4], klb[2][4];
#pragma unroll
  for (int t = 0; t < 4; ++t) {
    khb[0][t] = *(const bf16x8*)(kh_g + (kvbase + t * 16 + col) * 32 + 8 * grp);
    klb[0][t] = *(const bf16x8*)(kl_g + (kvbase + t * 16 + col) * 32 + 8 * grp);
  }

#pragma unroll 2
  for (int ch = 0; ch < 16; ++ch) {
    const int cur = ch & 1, nxt = cur ^ 1;
    const int key0 = ch * 64;
    bf16x8 vh[2][2], vl[2][2];
#pragma unroll
    for (int h = 0; h < 2; ++h)
#pragma unroll
      for (int s = 0; s < 2; ++s) {
        const size_t off = ((size_t)bth * 32 + h * 16 + col) * 1024 + key0 + s * 32 + 8 * grp;
        vh[h][s] = *(const bf16x8*)(vhT_g + off);
        vl[h][s] = *(const bf16x8*)(vlT_g + off);
      }
    if (ch < 15) {
#pragma unroll
      for (int t = 0; t < 4; ++t) {
        khb[nxt][t] = *(const bf16x8*)(kh_g + (kvbase + key0 + 64 + t * 16 + col) * 32 + 8 * grp);
        klb[nxt][t] = *(const bf16x8*)(kl_g + (kvbase + key0 + 64 + t * 16 + col) * 32 + 8 * grp);
      }
    }
    f32x4 s_[4];
#pragma unroll
    for (int t = 0; t < 4; ++t) {
      f32x4 a2 = {0.f, 0.f, 0.f, 0.f};
      a2 = __builtin_amdgcn_mfma_f32_16x16x32_bf16(qlf, khb[cur][t], a2, 0, 0, 0);
      a2 = __builtin_amdgcn_mfma_f32_16x16x32_bf16(qhf, klb[cur][t], a2, 0, 0, 0);
      a2 = __builtin_amdgcn_mfma_f32_16x16x32_bf16(qhf, khb[cur][t], a2, 0, 0, 0);
      s_[t] = a2;
    }
#pragma unroll
    for (int r = 0; r < 4; ++r) {
      float raw = fmaxf(fmaxf(s_[0][r], s_[1][r]), fmaxf(s_[2][r], s_[3][r]));
      raw = rmax16(raw);
      const float mm = raw * SCALE2;
      const float mn = fmaxf(mrow[r], mm);
      const float al = __builtin_amdgcn_exp2f(mrow[r] - mn);
      mrow[r] = mn;
      oc0[r] *= al;
      oc1[r] *= al;
      oc2[r] *= al;
#pragma unroll
      for (int t = 0; t < 4; ++t) {
        const float p = __builtin_amdgcn_exp2f(fmaf(s_[t][r], SCALE2, -mn));
        pb[(grp * 4 + r) * PSTR + t * 16 + col] = p;
      }
    }
    __builtin_amdgcn_wave_barrier();
    bf16x8 ph[2], pl[2];
#pragma unroll
    for (int s = 0; s < 2; ++s) {
      const f32x4 pa0 = *(const f32x4*)&pb[col * PSTR + s * 32 + 8 * grp];
      const f32x4 pa1 = *(const f32x4*)&pb[col * PSTR + s * 32 + 8 * grp + 4];
#pragma unroll
      for (int j = 0; j < 4; ++j) {
        const __bf16 h0 = (__bf16)pa0[j];
        ph[s][j] = h0;
        pl[s][j] = (__bf16)(pa0[j] - (float)h0);
        const __bf16 h1 = (__bf16)pa1[j];
        ph[s][4 + j] = h1;
        pl[s][4 + j] = (__bf16)(pa1[j] - (float)h1);
      }
    }
    __builtin_amdgcn_wave_barrier();
#pragma unroll
    for (int s = 0; s < 2; ++s) {
      oc0 = __builtin_amdgcn_mfma_f32_16x16x32_bf16(pl[s], vh[0][s], oc0, 0, 0, 0);
      oc0 = __builtin_amdgcn_mfma_f32_16x16x32_bf16(ph[s], vl[0][s], oc0, 0, 0, 0);
      oc0 = __builtin_amdgcn_mfma_f32_16x16x32_bf16(ph[s], vh[0][s], oc0, 0, 0, 0);
      oc1 = __builtin_amdgcn_mfma_f32_16x16x32_bf16(pl[s], vh[1][s], oc1, 0, 0, 0);
      oc1 = __builtin_amdgcn_mfma_f32_16x16x32_bf16(ph[s], vl[1][s], oc1, 0, 0, 0);
      oc1 = __builtin_amdgcn_mfma_f32_16x16x32_bf16(ph[s], vh[1][s], oc1, 0, 0, 0);
      oc2 = __builtin_amdgcn_mfma_f32_16x16x32_bf16(pl[s], onesf, oc2, 0, 0, 0);
      oc2 = __builtin_amdgcn_mfma_f32_16x16x32_bf16(ph[s], onesf, oc2, 0, 0, 0);
    }
  }

  __syncthreads();
#pragma unroll
  for (int r = 0; r < 4; ++r) {
    const int qq = w * 16 + grp * 4 + r;
    obuf[qq * 36 + col] = oc0[r];
    obuf[qq * 36 + 16 + col] = oc1[r];
    if (col == 0) {
      obuf[qq * 36 + 32] = mrow[r];
      obuf[qq * 36 + 33] = oc2[r];
    }
  }
  __syncthreads();

  if (tid < 64) {
    const int qq = tid;
    const int n = qt * 64 + qq;
    float M = obuf[qq * 36 + 32], L = obuf[qq * 36 + 33];
    float A[32];
#pragma unroll
    for (int d = 0; d < 32; ++d) A[d] = obuf[qq * 36 + d];
    float qrf[32];
    {
      const float* qp = qf + (kvbase + n) * 32;
#pragma unroll
      for (int d = 0; d < 32; ++d) qrf[d] = qp[d] * SCALE2;
    }
    const int pi = n >> 5, pj = n & 31;
    float sl[9];
#pragma unroll
    for (int tt = 0; tt < 9; ++tt) {
      const int ni = pi + tt / 3 - 1;
      const int nj = pj + tt % 3 - 1;
      const bool ok = (ni >= 0) && (ni < 32) && (nj >= 0) && (nj < 32);
      float s = -1e30f;
      if (ok) {
        const float* kr = kloc + (kvbase + ni * 32 + nj) * 32;
        float s0 = 0.f, s1 = 0.f, s2 = 0.f, s3 = 0.f;
#pragma unroll
        for (int d = 0; d < 32; d += 4) {
          s0 = fmaf(qrf[d + 0], kr[d + 0], s0);
          s1 = fmaf(qrf[d + 1], kr[d + 1], s1);
          s2 = fmaf(qrf[d + 2], kr[d + 2], s2);
          s3 = fmaf(qrf[d + 3], kr[d + 3], s3);
        }
        s = (s0 + s1) + (s2 + s3);
      }
      sl[tt] = s;
    }
    float tm = sl[0];
#pragma unroll
    for (int tt = 1; tt < 9; ++tt) tm = fmaxf(tm, sl[tt]);
    const float mn = fmaxf(M, tm);
    const float al = __builtin_amdgcn_exp2f(M - mn);
    M = mn;
    L *= al;
#pragma unroll
    for (int d = 0; d < 32; ++d) A[d] *= al;
#pragma unroll
    for (int tt = 0; tt < 9; ++tt) {
      const int ni = pi + tt / 3 - 1;
      const int nj = pj + tt % 3 - 1;
      const bool ok = (ni >= 0) && (ni < 32) && (nj >= 0) && (nj < 32);
      if (ok) {
        const float p = __builtin_amdgcn_exp2f(sl[tt] - mn);
        L += p;
        const float* vr = vloc + (kvbase + ni * 32 + nj) * 32;
#pragma unroll
        for (int d = 0; d < 32; ++d) A[d] = fmaf(p, vr[d], A[d]);
      }
    }
    const float inv = 1.0f / L;
    const int bt = bth >> 3, head = bth & 7;
    float* op = ctx + (((size_t)bt * 1024 + n) * 8 + head) * 32;
#pragma unroll
    for (int f = 0; f < 8; ++f) {
      float4 o;
      o.x = A[f * 4 + 0] * inv;
      o.y = A[f * 4 + 1] * inv;
      o.z = A[f * 4 + 2] * inv;
      o.w = A[f * 4 + 3] * inv;
      ((float4*)op)[f] = o;
    }
  }
}

// ---------------------------------------------------------------------------
// K4: out = ctx(8192x256) @ Wo^T via bf16x3 MFMA (both operands split during
// LDS staging from fp32). Same tile structure as proj. Epilogue: float4 over
// the 4 consecutive tokens held in C regs (out is token-contiguous).
// ---------------------------------------------------------------------------
__global__ __launch_bounds__(256) void outproj_kernel(const float* __restrict__ ctx,
                                                      const float* __restrict__ Wo,
                                                      float* __restrict__ out) {
  __shared__ __bf16 Ah[128 * ASTR], Al[128 * ASTR];
  __shared__ __bf16 Bh[128 * ASTR], Bl[128 * ASTR];
  const int m0 = blockIdx.x * 128;
  const int o0 = blockIdx.y * 128;
  const int tid = threadIdx.x;
  const int w = tid >> 6, lane = tid & 63;
  const int col = lane & 15, grp = lane >> 4;
  const int mq = (w & 1) * 64, nq = (w >> 1) * 64;
  f32x4 acc[4][4];
#pragma unroll
  for (int i = 0; i < 4; ++i)
#pragma unroll
    for (int j = 0; j < 4; ++j) acc[i][j] = (f32x4){0.f, 0.f, 0.f, 0.f};

#pragma unroll 1
  for (int k0 = 0; k0 < 256; k0 += 32) {
    const int sg = tid & 7;
#pragma unroll
    for (int p = 0; p < 4; ++p) {
      const int m = p * 32 + (tid >> 3);
      const float4 f = *(const float4*)(ctx + (size_t)(m0 + m) * 256 + k0 + sg * 4);
      bf16x4 h, l;
      h[0] = (__bf16)f.x; l[0] = (__bf16)(f.x - (float)h[0]);
      h[1] = (__bf16)f.y; l[1] = (__bf16)(f.y - (float)h[1]);
      h[2] = (__bf16)f.z; l[2] = (__bf16)(f.z - (float)h[2]);
      h[3] = (__bf16)f.w; l[3] = (__bf16)(f.w - (float)h[3]);
      *(bf16x4*)&Ah[m * ASTR + sg * 4] = h;
      *(bf16x4*)&Al[m * ASTR + sg * 4] = l;
    }
#pragma unroll
    for (int p = 0; p < 4; ++p) {
      const int o = p * 32 + (tid >> 3);
      const float4 f = *(const float4*)(Wo + (size_t)(o0 + o) * 256 + k0 + sg * 4);
      bf16x4 h, l;
      h[0] = (__bf16)f.x; l[0] = (__bf16)(f.x - (float)h[0]);
      h[1] = (__bf16)f.y; l[1] = (__bf16)(f.y - (float)h[1]);
      h[2] = (__bf16)f.z; l[2] = (__bf16)(f.z - (float)h[2]);
      h[3] = (__bf16)f.w; l[3] = (__bf16)(f.w - (float)h[3]);
      *(bf16x4*)&Bh[o * ASTR + sg * 4] = h;
      *(bf16x4*)&Bl[o * ASTR + sg * 4] = l;
    }
    __syncthreads();
    bf16x8 ah[4], al[4], bh[4], bl[4];
#pragma unroll
    for (int mi = 0; mi < 4; ++mi) {
      ah[mi] = *(const bf16x8*)&Ah[(mq + mi * 16 + col) * ASTR + 8 * grp];
      al[mi] = *(const bf16x8*)&Al[(mq + mi * 16 + col) * ASTR + 8 * grp];
    }
#pragma unroll
    for (int ni = 0; ni < 4; ++ni) {
      bh[ni] = *(const bf16x8*)&Bh[(nq + ni * 16 + col) * ASTR + 8 * grp];
      bl[ni] = *(const bf16x8*)&Bl[(nq + ni * 16 + col) * ASTR + 8 * grp];
    }
#pragma unroll
    for (int mi = 0; mi < 4; ++mi)
#pragma unroll
      for (int ni = 0; ni < 4; ++ni) {
        acc[mi][ni] = __builtin_amdgcn_mfma_f32_16x16x32_bf16(al[mi], bh[ni], acc[mi][ni], 0, 0, 0);
        acc[mi][ni] = __builtin_amdgcn_mfma_f32_16x16x32_bf16(ah[mi], bl[ni], acc[mi][ni], 0, 0, 0);
        acc[mi][ni] = __builtin_amdgcn_mfma_f32_16x16x32_bf16(ah[mi], bh[ni], acc[mi][ni], 0, 0, 0);
      }
    __syncthreads();
  }
#pragma unroll
  for (int mi = 0; mi < 4; ++mi) {
    const int mb = m0 + mq + mi * 16 + grp * 4;
    const int bt = mb >> 10;
    const int nb = mb & 1023;
    const int b = bt >> 2, t = bt & 3;
#pragma unroll
    for (int ni = 0; ni < 4; ++ni) {
      const int o = o0 + nq + ni * 16 + col;
      const float4 f4 = make_float4(acc[mi][ni][0], acc[mi][ni][1],
                                    acc[mi][ni][2], acc[mi][ni][3]);
      *(float4*)&out[((size_t)(b * 256 + o) * 4 + t) * 1024 + nb] = f4;
    }
  }
}

extern "C" void kernel_launch(void* const* d_in, const int* in_sizes, int n_in,
                              void* d_out, int out_size, void* d_ws, size_t ws_size,
                              hipStream_t stream) {
  const float* x = (const float*)d_in[0];
  const float* gamma = (const float*)d_in[1];
  const float* beta = (const float*)d_in[2];
  const float* Wq = (const float*)d_in[3];
  const float* Wk = (const float*)d_in[4];
  const float* Wv = (const float*)d_in[5];
  const float* Wkl = (const float*)d_in[6];
  const float* Wvl = (const float*)d_in[7];
  const float* Wo = (const float*)d_in[8];
  const float* qb = (const float*)d_in[9];

  // Workspace (56 MB): ctx overlays xn_h/xn_l (xn dead after proj).
  char* base = (char*)d_ws;
  const size_t MB = 1024 * 1024;
  __bf16* xnh = (__bf16*)(base + 0);        // 4 MB
  __bf16* xnl = (__bf16*)(base + 4 * MB);   // 4 MB
  float* ctx = (float*)(base + 0);          // 8 MB (overlay)
  float* qf = (float*)(base + 8 * MB);      // 8 MB
  float* kloc = (float*)(base + 16 * MB);   // 8 MB
  float* vloc = (float*)(base + 24 * MB);   // 8 MB
  __bf16* qh = (__bf16*)(base + 32 * MB);   // 4 MB each
  __bf16* ql = (__bf16*)(base + 36 * MB);
  __bf16* kh = (__bf16*)(base + 40 * MB);
  __bf16* kl = (__bf16*)(base + 44 * MB);
  __bf16* vhT = (__bf16*)(base + 48 * MB);
  __bf16* vlT = (__bf16*)(base + 52 * MB);

  hipLaunchKernelGGL(ln_kernel, dim3(256), dim3(256), 0, stream, x, gamma, beta,
                     xnh, xnl);
  hipLaunchKernelGGL(proj_kernel, dim3(64, 2, 5), dim3(256), 0, stream, xnh, xnl,
                     Wq, Wk, Wv, Wkl, Wvl, qb, qf, qh, ql, kh, kl, vhT, vlT,
                     kloc, vloc);
  hipLaunchKernelGGL(attn_kernel, dim3(64, 16), dim3(256), 0, stream, qh, ql, kh,
                     kl, vhT, vlT, qf, kloc, vloc, ctx);
  hipLaunchKernelGGL(outproj_kernel, dim3(64, 2), dim3(256), 0, stream, ctx, Wo,
                     (float*)d_out);
}

// Round 8
// 251.495 us; speedup vs baseline: 1.3415x; 1.0004x over previous
//
#include <hip/hip_runtime.h>

#define NROWS 8192  // BT * N = 8 * 1024
#define MCONST 8.0f // fixed softmax max-bound (scores*scale*log2e max ~0.9)

typedef float f32x4 __attribute__((ext_vector_type(4)));
typedef __bf16 bf16x8 __attribute__((ext_vector_type(8)));
typedef __bf16 bf16x4 __attribute__((ext_vector_type(4)));

// ---------------------------------------------------------------------------
// K1: LayerNorm over D=256 -> row-major bf16 hi/lo xn pair [token][d].
// ---------------------------------------------------------------------------
__global__ __launch_bounds__(256) void ln_kernel(const float* __restrict__ x,
                                                 const float* __restrict__ gamma,
                                                 const float* __restrict__ beta,
                                                 __bf16* __restrict__ xnh,
                                                 __bf16* __restrict__ xnl) {
  __shared__ float red[2][8][32];
  const int blk = blockIdx.x;  // 256 = bt(8) x nchunk(32)
  const int bt = blk >> 5;
  const int b = bt >> 2, t = bt & 3;
  const int n0 = (blk & 31) << 5;
  const int part = threadIdx.x >> 5, r = threadIdx.x & 31;
  const int n = n0 + r;
  const float* xp = x + ((size_t)(b * 256) * 4 + t) * 1024 + n;  // d stride 4096
  float sum = 0.f, sumsq = 0.f;
#pragma unroll 8
  for (int dd = 0; dd < 32; ++dd) {
    float vv = xp[(size_t)(part * 32 + dd) * 4096];
    sum += vv;
    sumsq += vv * vv;
  }
  red[0][part][r] = sum;
  red[1][part][r] = sumsq;
  __syncthreads();
  float s1 = 0.f, s2 = 0.f;
#pragma unroll
  for (int p = 0; p < 8; ++p) {
    s1 += red[0][p][r];
    s2 += red[1][p][r];
  }
  const float mu = s1 * (1.0f / 256.0f);
  const float var = s2 * (1.0f / 256.0f) - mu * mu;
  const float rstd = rsqrtf(var + 1e-6f);
  const size_t row = (size_t)bt * 1024 + n;
  __bf16 hbuf[32], lbuf[32];
#pragma unroll 8
  for (int dd = 0; dd < 32; ++dd) {
    const int d = part * 32 + dd;
    float vv = xp[(size_t)d * 4096];
    const float val = (vv - mu) * rstd * gamma[d] + beta[d];
    const __bf16 h = (__bf16)val;
    hbuf[dd] = h;
    lbuf[dd] = (__bf16)(val - (float)h);
  }
  __bf16* oh = xnh + row * 256 + part * 32;
  __bf16* ol = xnl + row * 256 + part * 32;
#pragma unroll
  for (int f = 0; f < 4; ++f) {
    *(bf16x8*)(oh + f * 8) = *(bf16x8*)&hbuf[f * 8];
    *(bf16x8*)(ol + f * 8) = *(bf16x8*)&lbuf[f * 8];
  }
}

// ---------------------------------------------------------------------------
// K0: split all 6 weight matrices fp32 -> bf16 hi/lo, once per call.
// ---------------------------------------------------------------------------
__global__ __launch_bounds__(256) void wsplit_kernel(
    const float* __restrict__ Wq, const float* __restrict__ Wk,
    const float* __restrict__ Wv, const float* __restrict__ Wkl,
    const float* __restrict__ Wvl, const float* __restrict__ Wo,
    __bf16* __restrict__ wh, __bf16* __restrict__ wl) {
  const int gid = blockIdx.x * 256 + threadIdx.x;  // 98304 = 6 * 16384
  const int mat = gid >> 14;
  const int off = (gid & 16383) * 4;
  const float* W = (mat == 0) ? Wq : (mat == 1) ? Wk : (mat == 2) ? Wv
                   : (mat == 3) ? Wkl : (mat == 4) ? Wvl : Wo;
  const float4 f = *(const float4*)(W + off);
  bf16x4 h, l;
  h[0] = (__bf16)f.x; l[0] = (__bf16)(f.x - (float)h[0]);
  h[1] = (__bf16)f.y; l[1] = (__bf16)(f.y - (float)h[1]);
  h[2] = (__bf16)f.z; l[2] = (__bf16)(f.z - (float)h[2]);
  h[3] = (__bf16)f.w; l[3] = (__bf16)(f.w - (float)h[3]);
  *(bf16x4*)(wh + (size_t)mat * 65536 + off) = h;
  *(bf16x4*)(wl + (size_t)mat * 65536 + off) = l;
}

// ---------------------------------------------------------------------------
// K2: 5 projections via bf16x3 MFMA; both operands pre-split -> staging is
// pure bf16x8 copies. Tile 128x128, BK=32, 4 waves x (64x64).
// ---------------------------------------------------------------------------
#define ASTR 40
__global__ __launch_bounds__(256) void proj_kernel(
    const __bf16* __restrict__ xnh, const __bf16* __restrict__ xnl,
    const __bf16* __restrict__ wh, const __bf16* __restrict__ wl,
    const float* __restrict__ qb,
    __bf16* __restrict__ qh_g, __bf16* __restrict__ ql_g,
    __bf16* __restrict__ kh_g, __bf16* __restrict__ kl_g,
    __bf16* __restrict__ vhT_g, __bf16* __restrict__ vlT_g,
    float* __restrict__ kloc, float* __restrict__ vloc) {
  __shared__ __bf16 Ah[128 * ASTR], Al[128 * ASTR];
  __shared__ __bf16 Bh[128 * ASTR], Bl[128 * ASTR];
  const int z = blockIdx.z;
  const __bf16* Wh = wh + (size_t)z * 65536;
  const __bf16* Wl = wl + (size_t)z * 65536;
  const int m0 = blockIdx.x * 128;
  const int o0 = blockIdx.y * 128;
  const int tid = threadIdx.x;
  const int w = tid >> 6, lane = tid & 63;
  const int col = lane & 15, grp = lane >> 4;
  const int mq = (w & 1) * 64, nq = (w >> 1) * 64;
  f32x4 acc[4][4];
#pragma unroll
  for (int i = 0; i < 4; ++i)
#pragma unroll
    for (int j = 0; j < 4; ++j) acc[i][j] = (f32x4){0.f, 0.f, 0.f, 0.f};

#pragma unroll 1
  for (int k0 = 0; k0 < 256; k0 += 32) {
    const int sg = tid & 3, rowq = tid >> 2;
#pragma unroll
    for (int p = 0; p < 2; ++p) {
      const int m = p * 64 + rowq;
      const size_t srcA = (size_t)(m0 + m) * 256 + k0 + sg * 8;
      *(bf16x8*)&Ah[m * ASTR + sg * 8] = *(const bf16x8*)(xnh + srcA);
      *(bf16x8*)&Al[m * ASTR + sg * 8] = *(const bf16x8*)(xnl + srcA);
      const size_t srcB = (size_t)(o0 + m) * 256 + k0 + sg * 8;
      *(bf16x8*)&Bh[m * ASTR + sg * 8] = *(const bf16x8*)(Wh + srcB);
      *(bf16x8*)&Bl[m * ASTR + sg * 8] = *(const bf16x8*)(Wl + srcB);
    }
    __syncthreads();
    bf16x8 ah[4], al[4], bh[4], bl[4];
#pragma unroll
    for (int mi = 0; mi < 4; ++mi) {
      ah[mi] = *(const bf16x8*)&Ah[(mq + mi * 16 + col) * ASTR + 8 * grp];
      al[mi] = *(const bf16x8*)&Al[(mq + mi * 16 + col) * ASTR + 8 * grp];
    }
#pragma unroll
    for (int ni = 0; ni < 4; ++ni) {
      bh[ni] = *(const bf16x8*)&Bh[(nq + ni * 16 + col) * ASTR + 8 * grp];
      bl[ni] = *(const bf16x8*)&Bl[(nq + ni * 16 + col) * ASTR + 8 * grp];
    }
#pragma unroll
    for (int mi = 0; mi < 4; ++mi)
#pragma unroll
      for (int ni = 0; ni < 4; ++ni) {
        acc[mi][ni] = __builtin_amdgcn_mfma_f32_16x16x32_bf16(al[mi], bh[ni], acc[mi][ni], 0, 0, 0);
        acc[mi][ni] = __builtin_amdgcn_mfma_f32_16x16x32_bf16(ah[mi], bl[ni], acc[mi][ni], 0, 0, 0);
        acc[mi][ni] = __builtin_amdgcn_mfma_f32_16x16x32_bf16(ah[mi], bh[ni], acc[mi][ni], 0, 0, 0);
      }
    __syncthreads();
  }
#pragma unroll
  for (int mi = 0; mi < 4; ++mi) {
    const int mb = m0 + mq + mi * 16 + grp * 4;
    const int bt = mb >> 10;
    const int nb = mb & 1023;
#pragma unroll
    for (int ni = 0; ni < 4; ++ni) {
      const int o = o0 + nq + ni * 16 + col;
      const int head = o >> 5, dh = o & 31;
      const int bth = bt * 8 + head;
      if (z == 2) {
        bf16x4 hv, lv;
#pragma unroll
        for (int r = 0; r < 4; ++r) {
          const float val = acc[mi][ni][r];
          const __bf16 h = (__bf16)val;
          hv[r] = h;
          lv[r] = (__bf16)(val - (float)h);
        }
        const size_t tix = ((size_t)bth * 32 + dh) * 1024 + nb;
        *(bf16x4*)(vhT_g + tix) = hv;
        *(bf16x4*)(vlT_g + tix) = lv;
      } else if (z <= 1) {
        const float qbo = (z == 0) ? qb[o] : 0.f;
#pragma unroll
        for (int r = 0; r < 4; ++r) {
          const float val = acc[mi][ni][r] + qbo;
          const size_t idx = ((size_t)bth * 1024 + nb + r) * 32 + dh;
          const __bf16 h = (__bf16)val;
          if (z == 0) {
            qh_g[idx] = h;
            ql_g[idx] = (__bf16)(val - (float)h);
          } else {
            kh_g[idx] = h;
            kl_g[idx] = (__bf16)(val - (float)h);
          }
        }
      } else {
        float* dst = (z == 3) ? kloc : vloc;
#pragma unroll
        for (int r = 0; r < 4; ++r)
          dst[((size_t)bth * 1024 + nb + r) * 32 + dh] = acc[mi][ni][r];
      }
    }
  }
}

// ---------------------------------------------------------------------------
// K3: MFMA flash attention with FIXED-MAX softmax (M=8): no running max, no
// rescales, no shuffles -- p = exp2(s*scale - 8); O,l accumulate freely and
// 2^-8 cancels at normalize. Writes unnormalized O + l; finish kernel does
// the local 3x3 + normalize. XCD swizzle + K reg double-buffer kept.
// ---------------------------------------------------------------------------
#define PSTR 68
__global__ __launch_bounds__(256) void attn_kernel(
    const __bf16* __restrict__ qh_g, const __bf16* __restrict__ ql_g,
    const __bf16* __restrict__ kh_g, const __bf16* __restrict__ kl_g,
    const __bf16* __restrict__ vhT_g, const __bf16* __restrict__ vlT_g,
    float* __restrict__ opart, float* __restrict__ lpart) {
  __shared__ float pbs[4][16 * PSTR];
  const int bth = blockIdx.x, qt = blockIdx.y;
  const int tid = threadIdx.x;
  const int w = tid >> 6, lane = tid & 63;
  const int col = lane & 15, grp = lane >> 4;
  const int m0 = qt * 64 + w * 16;
  const float SCALE2 = 0.17677669529663687f * 1.4426950408889634f;  // dh^-.5*log2e
  const size_t kvbase = (size_t)bth << 10;
  float* pb = pbs[w];

  bf16x8 onesf;
#pragma unroll
  for (int j = 0; j < 8; ++j) onesf[j] = (__bf16)1.0f;

  const bf16x8 qhf = *(const bf16x8*)(qh_g + (kvbase + m0 + col) * 32 + 8 * grp);
  const bf16x8 qlf = *(const bf16x8*)(ql_g + (kvbase + m0 + col) * 32 + 8 * grp);

  f32x4 oc0 = {0.f, 0.f, 0.f, 0.f}, oc1 = {0.f, 0.f, 0.f, 0.f};
  f32x4 oc2 = {0.f, 0.f, 0.f, 0.f};

  bf16x8 khb[2][4], klb[2][4];
#pragma unroll
  for (int t = 0; t < 4; ++t) {
    khb[0][t] = *(const bf16x8*)(kh_g + (kvbase + t * 16 + col) * 32 + 8 * grp);
    klb[0][t] = *(const bf16x8*)(kl_g + (kvbase + t * 16 + col) * 32 + 8 * grp);
  }

#pragma unroll 2
  for (int ch = 0; ch < 16; ++ch) {
    const int cur = ch & 1, nxt = cur ^ 1;
    const int key0 = ch * 64;
    bf16x8 vh[2][2], vl[2][2];
#pragma unroll
    for (int h = 0; h < 2; ++h)
#pragma unroll
      for (int s = 0; s < 2; ++s) {
        const size_t off = ((size_t)bth * 32 + h * 16 + col) * 1024 + key0 + s * 32 + 8 * grp;
        vh[h][s] = *(const bf16x8*)(vhT_g + off);
        vl[h][s] = *(const bf16x8*)(vlT_g + off);
      }
    if (ch < 15) {
#pragma unroll
      for (int t = 0; t < 4; ++t) {
        khb[nxt][t] = *(const bf16x8*)(kh_g + (kvbase + key0 + 64 + t * 16 + col) * 32 + 8 * grp);
        klb[nxt][t] = *(const bf16x8*)(kl_g + (kvbase + key0 + 64 + t * 16 + col) * 32 + 8 * grp);
      }
    }
    f32x4 s_[4];
#pragma unroll
    for (int t = 0; t < 4; ++t) {
      f32x4 a2 = {0.f, 0.f, 0.f, 0.f};
      a2 = __builtin_amdgcn_mfma_f32_16x16x32_bf16(qlf, khb[cur][t], a2, 0, 0, 0);
      a2 = __builtin_amdgcn_mfma_f32_16x16x32_bf16(qhf, klb[cur][t], a2, 0, 0, 0);
      a2 = __builtin_amdgcn_mfma_f32_16x16x32_bf16(qhf, khb[cur][t], a2, 0, 0, 0);
      s_[t] = a2;
    }
    // fixed-max softmax: independent exp2 per score, no cross-lane ops
#pragma unroll
    for (int r = 0; r < 4; ++r)
#pragma unroll
      for (int t = 0; t < 4; ++t) {
        const float p = __builtin_amdgcn_exp2f(fmaf(s_[t][r], SCALE2, -MCONST));
        pb[(grp * 4 + r) * PSTR + t * 16 + col] = p;
      }
    __builtin_amdgcn_wave_barrier();
    bf16x8 ph[2], pl[2];
#pragma unroll
    for (int s = 0; s < 2; ++s) {
      const f32x4 pa0 = *(const f32x4*)&pb[col * PSTR + s * 32 + 8 * grp];
      const f32x4 pa1 = *(const f32x4*)&pb[col * PSTR + s * 32 + 8 * grp + 4];
#pragma unroll
      for (int j = 0; j < 4; ++j) {
        const __bf16 h0 = (__bf16)pa0[j];
        ph[s][j] = h0;
        pl[s][j] = (__bf16)(pa0[j] - (float)h0);
        const __bf16 h1 = (__bf16)pa1[j];
        ph[s][4 + j] = h1;
        pl[s][4 + j] = (__bf16)(pa1[j] - (float)h1);
      }
    }
    __builtin_amdgcn_wave_barrier();
#pragma unroll
    for (int s = 0; s < 2; ++s) {
      oc0 = __builtin_amdgcn_mfma_f32_16x16x32_bf16(pl[s], vh[0][s], oc0, 0, 0, 0);
      oc0 = __builtin_amdgcn_mfma_f32_16x16x32_bf16(ph[s], vl[0][s], oc0, 0, 0, 0);
      oc0 = __builtin_amdgcn_mfma_f32_16x16x32_bf16(ph[s], vh[0][s], oc0, 0, 0, 0);
      oc1 = __builtin_amdgcn_mfma_f32_16x16x32_bf16(pl[s], vh[1][s], oc1, 0, 0, 0);
      oc1 = __builtin_amdgcn_mfma_f32_16x16x32_bf16(ph[s], vl[1][s], oc1, 0, 0, 0);
      oc1 = __builtin_amdgcn_mfma_f32_16x16x32_bf16(ph[s], vh[1][s], oc1, 0, 0, 0);
      oc2 = __builtin_amdgcn_mfma_f32_16x16x32_bf16(pl[s], onesf, oc2, 0, 0, 0);
      oc2 = __builtin_amdgcn_mfma_f32_16x16x32_bf16(ph[s], onesf, oc2, 0, 0, 0);
    }
  }

  // write unnormalized O and l straight to global (no LDS, no tail pass)
#pragma unroll
  for (int r = 0; r < 4; ++r) {
    const size_t row = kvbase + m0 + grp * 4 + r;
    float* Op = opart + row * 32;
    Op[col] = oc0[r];
    Op[16 + col] = oc1[r];
    if (col == 0) lpart[row] = oc2[r];
  }
}

// ---------------------------------------------------------------------------
// K3b: finish -- local 3x3 tile (fixed-max), merge, normalize, write ctx
// row-major [token][head*32+dh] as bf16 hi/lo (A operand of outproj).
// One thread per (bth, n) row.
// ---------------------------------------------------------------------------
__global__ __launch_bounds__(256) void finish_kernel(
    const float* __restrict__ opart, const float* __restrict__ lpart,
    const __bf16* __restrict__ qh_g, const __bf16* __restrict__ ql_g,
    const float* __restrict__ kloc, const float* __restrict__ vloc,
    __bf16* __restrict__ ctxh, __bf16* __restrict__ ctxl) {
  const int gid = blockIdx.x * 256 + threadIdx.x;  // 65536 rows
  const int bth = gid >> 10, n = gid & 1023;
  const float SCALE2 = 0.17677669529663687f * 1.4426950408889634f;
  const size_t kvbase = (size_t)bth << 10;
  float qrf[32];
  {
    const __bf16* qh = qh_g + (kvbase + n) * 32;
    const __bf16* ql = ql_g + (kvbase + n) * 32;
#pragma unroll
    for (int d = 0; d < 32; ++d)
      qrf[d] = ((float)qh[d] + (float)ql[d]) * SCALE2;
  }
  float A[32];
  {
    const float* Op = opart + (size_t)gid * 32;
#pragma unroll
    for (int f = 0; f < 8; ++f) *(float4*)&A[f * 4] = *(const float4*)(Op + f * 4);
  }
  float L = lpart[gid];
  const int pi = n >> 5, pj = n & 31;
#pragma unroll
  for (int tt = 0; tt < 9; ++tt) {
    const int ni = pi + tt / 3 - 1;
    const int nj = pj + tt % 3 - 1;
    const bool ok = (ni >= 0) && (ni < 32) && (nj >= 0) && (nj < 32);
    if (ok) {
      const float* kr = kloc + (kvbase + ni * 32 + nj) * 32;
      float s0 = 0.f, s1 = 0.f, s2 = 0.f, s3 = 0.f;
#pragma unroll
      for (int d = 0; d < 32; d += 4) {
        s0 = fmaf(qrf[d + 0], kr[d + 0], s0);
        s1 = fmaf(qrf[d + 1], kr[d + 1], s1);
        s2 = fmaf(qrf[d + 2], kr[d + 2], s2);
        s3 = fmaf(qrf[d + 3], kr[d + 3], s3);
      }
      const float p = __builtin_amdgcn_exp2f(((s0 + s1) + (s2 + s3)) - MCONST);
      L += p;
      const float* vr = vloc + (kvbase + ni * 32 + nj) * 32;
#pragma unroll
      for (int d = 0; d < 32; ++d) A[d] = fmaf(p, vr[d], A[d]);
    }
  }
  const float inv = 1.0f / L;
  const int bt = bth >> 3, head = bth & 7;
  __bf16 hb[32], lb[32];
#pragma unroll
  for (int d = 0; d < 32; ++d) {
    const float val = A[d] * inv;
    const __bf16 h = (__bf16)val;
    hb[d] = h;
    lb[d] = (__bf16)(val - (float)h);
  }
  const size_t cb = ((size_t)(bt * 1024 + n)) * 256 + head * 32;
#pragma unroll
  for (int f = 0; f < 4; ++f) {
    *(bf16x8*)(ctxh + cb + f * 8) = *(bf16x8*)&hb[f * 8];
    *(bf16x8*)(ctxl + cb + f * 8) = *(bf16x8*)&lb[f * 8];
  }
}

// ---------------------------------------------------------------------------
// K4: out = ctx(8192x256) @ Wo^T via bf16x3 MFMA; both operands pre-split.
// ---------------------------------------------------------------------------
__global__ __launch_bounds__(256) void outproj_kernel(
    const __bf16* __restrict__ ctxh, const __bf16* __restrict__ ctxl,
    const __bf16* __restrict__ woh, const __bf16* __restrict__ wol,
    float* __restrict__ out) {
  __shared__ __bf16 Ah[128 * ASTR], Al[128 * ASTR];
  __shared__ __bf16 Bh[128 * ASTR], Bl[128 * ASTR];
  const int m0 = blockIdx.x * 128;
  const int o0 = blockIdx.y * 128;
  const int tid = threadIdx.x;
  const int w = tid >> 6, lane = tid & 63;
  const int col = lane & 15, grp = lane >> 4;
  const int mq = (w & 1) * 64, nq = (w >> 1) * 64;
  f32x4 acc[4][4];
#pragma unroll
  for (int i = 0; i < 4; ++i)
#pragma unroll
    for (int j = 0; j < 4; ++j) acc[i][j] = (f32x4){0.f, 0.f, 0.f, 0.f};

#pragma unroll 1
  for (int k0 = 0; k0 < 256; k0 += 32) {
    const int sg = tid & 3, rowq = tid >> 2;
#pragma unroll
    for (int p = 0; p < 2; ++p) {
      const int m = p * 64 + rowq;
      const size_t srcA = (size_t)(m0 + m) * 256 + k0 + sg * 8;
      *(bf16x8*)&Ah[m * ASTR + sg * 8] = *(const bf16x8*)(ctxh + srcA);
      *(bf16x8*)&Al[m * ASTR + sg * 8] = *(const bf16x8*)(ctxl + srcA);
      const size_t srcB = (size_t)(o0 + m) * 256 + k0 + sg * 8;
      *(bf16x8*)&Bh[m * ASTR + sg * 8] = *(const bf16x8*)(woh + srcB);
      *(bf16x8*)&Bl[m * ASTR + sg * 8] = *(const bf16x8*)(wol + srcB);
    }
    __syncthreads();
    bf16x8 ah[4], al[4], bh[4], bl[4];
#pragma unroll
    for (int mi = 0; mi < 4; ++mi) {
      ah[mi] = *(const bf16x8*)&Ah[(mq + mi * 16 + col) * ASTR + 8 * grp];
      al[mi] = *(const bf16x8*)&Al[(mq + mi * 16 + col) * ASTR + 8 * grp];
    }
#pragma unroll
    for (int ni = 0; ni < 4; ++ni) {
      bh[ni] = *(const bf16x8*)&Bh[(nq + ni * 16 + col) * ASTR + 8 * grp];
      bl[ni] = *(const bf16x8*)&Bl[(nq + ni * 16 + col) * ASTR + 8 * grp];
    }
#pragma unroll
    for (int mi = 0; mi < 4; ++mi)
#pragma unroll
      for (int ni = 0; ni < 4; ++ni) {
        acc[mi][ni] = __builtin_amdgcn_mfma_f32_16x16x32_bf16(al[mi], bh[ni], acc[mi][ni], 0, 0, 0);
        acc[mi][ni] = __builtin_amdgcn_mfma_f32_16x16x32_bf16(ah[mi], bl[ni], acc[mi][ni], 0, 0, 0);
        acc[mi][ni] = __builtin_amdgcn_mfma_f32_16x16x32_bf16(ah[mi], bh[ni], acc[mi][ni], 0, 0, 0);
      }
    __syncthreads();
  }
#pragma unroll
  for (int mi = 0; mi < 4; ++mi) {
    const int mb = m0 + mq + mi * 16 + grp * 4;
    const int bt = mb >> 10;
    const int nb = mb & 1023;
    const int b = bt >> 2, t = bt & 3;
#pragma unroll
    for (int ni = 0; ni < 4; ++ni) {
      const int o = o0 + nq + ni * 16 + col;
      const float4 f4 = make_float4(acc[mi][ni][0], acc[mi][ni][1],
                                    acc[mi][ni][2], acc[mi][ni][3]);
      *(float4*)&out[((size_t)(b * 256 + o) * 4 + t) * 1024 + nb] = f4;
    }
  }
}

extern "C" void kernel_launch(void* const* d_in, const int* in_sizes, int n_in,
                              void* d_out, int out_size, void* d_ws, size_t ws_size,
                              hipStream_t stream) {
  const float* x = (const float*)d_in[0];
  const float* gamma = (const float*)d_in[1];
  const float* beta = (const float*)d_in[2];
  const float* Wq = (const float*)d_in[3];
  const float* Wk = (const float*)d_in[4];
  const float* Wv = (const float*)d_in[5];
  const float* Wkl = (const float*)d_in[6];
  const float* Wvl = (const float*)d_in[7];
  const float* Wo = (const float*)d_in[8];
  const float* qb = (const float*)d_in[9];

  // Workspace map (50 MB). Overlays: opart over xn (dead after proj);
  // ctx over vhT/vlT (dead after attn).
  char* base = (char*)d_ws;
  const size_t MB = 1024 * 1024;
  __bf16* xnh = (__bf16*)(base + 0);         // 4 MB
  __bf16* xnl = (__bf16*)(base + 4 * MB);    // 4 MB
  float* opart = (float*)(base + 0);         // 8 MB overlay
  __bf16* wh = (__bf16*)(base + 8 * MB);     // 0.75 MB (6 mats)
  __bf16* wl = (__bf16*)(base + 8 * MB + 768 * 1024);  // 0.75 MB
  float* lpart = (float*)(base + 9 * MB + 512 * 1024); // 0.25 MB
  __bf16* qh = (__bf16*)(base + 10 * MB);    // 4 MB
  __bf16* ql = (__bf16*)(base + 14 * MB);
  __bf16* kh = (__bf16*)(base + 18 * MB);
  __bf16* kl = (__bf16*)(base + 22 * MB);
  __bf16* vhT = (__bf16*)(base + 26 * MB);
  __bf16* vlT = (__bf16*)(base + 30 * MB);
  __bf16* ctxh = (__bf16*)(base + 26 * MB);  // overlay vhT
  __bf16* ctxl = (__bf16*)(base + 30 * MB);  // overlay vlT
  float* kloc = (float*)(base + 34 * MB);    // 8 MB
  float* vloc = (float*)(base + 42 * MB);    // 8 MB

  hipLaunchKernelGGL(ln_kernel, dim3(256), dim3(256), 0, stream, x, gamma, beta,
                     xnh, xnl);
  hipLaunchKernelGGL(wsplit_kernel, dim3(384), dim3(256), 0, stream, Wq, Wk, Wv,
                     Wkl, Wvl, Wo, wh, wl);
  hipLaunchKernelGGL(proj_kernel, dim3(64, 2, 5), dim3(256), 0, stream, xnh, xnl,
                     wh, wl, qb, qh, ql, kh, kl, vhT, vlT, kloc, vloc);
  hipLaunchKernelGGL(attn_kernel, dim3(64, 16), dim3(256), 0, stream, qh, ql, kh,
                     kl, vhT, vlT, opart, lpart);
  hipLaunchKernelGGL(finish_kernel, dim3(256), dim3(256), 0, stream, opart, lpart,
                     qh, ql, kloc, vloc, ctxh, ctxl);
  hipLaunchKernelGGL(outproj_kernel, dim3(64, 2), dim3(256), 0, stream, ctxh, ctxl,
                     wh + (size_t)5 * 65536, wl + (size_t)5 * 65536, (float*)d_out);
}